// Round 1
// baseline (5118.595 us; speedup 1.0000x reference)
//
#include <hip/hip_runtime.h>
#include <hip/hip_bf16.h>

#define N_NODES 50000
#define N_EDGES 800000
#define DIM 128
#define HID 256
#define N_GRAPH 512
#define N_LAYER 3
#define EFEAT 8
#define BN_EPS 1e-5f

// ---------------------------------------------------------------- utilities

__device__ __forceinline__ void atomic_add_f(float* p, float v) {
    unsafeAtomicAdd(p, v);   // global_atomic_add_f32 on gfx90a+ (no CAS loop)
}

// ---------------------------------------------------------------- init vn
__global__ void init_vn_kernel(const float* __restrict__ vn_emb, float* __restrict__ vn) {
    int idx = blockIdx.x * 256 + threadIdx.x;
    if (idx < N_GRAPH * DIM) vn[idx] = vn_emb[idx & (DIM - 1)];
}

// ---------------------------------------------------------------- h_in = act(src) + vn[batch]
// USEBN: src is pre-BN h from previous layer; apply alpha*x+beta then relu
template <bool USEBN>
__global__ __launch_bounds__(256) void hin_kernel(
    const float* __restrict__ src,
    const float* __restrict__ sum2, const float* __restrict__ ss2,
    const float* __restrict__ g, const float* __restrict__ b, float invN,
    const int* __restrict__ batch, const float* __restrict__ vn,
    float* __restrict__ hin, int total4)
{
    int idx = blockIdx.x * 256 + threadIdx.x;
    if (idx >= total4) return;
    int base = idx * 4;
    int n = base >> 7;          // /128
    int c = base & (DIM - 1);
    float4 v = *(const float4*)(src + base);
    if (USEBN) {
        float o[4] = {v.x, v.y, v.z, v.w};
        #pragma unroll
        for (int j = 0; j < 4; ++j) {
            int cj = c + j;
            float m = sum2[cj] * invN;
            float var = ss2[cj] * invN - m * m;
            float r = rsqrtf(var + BN_EPS);
            float a = g[cj] * r;
            float be_ = b[cj] - m * a;
            o[j] = fmaxf(fmaf(a, o[j], be_), 0.f);
        }
        v.x = o[0]; v.y = o[1]; v.z = o[2]; v.w = o[3];
    }
    int grp = batch[n];
    const float4 w = *(const float4*)(vn + grp * DIM + c);
    v.x += w.x; v.y += w.y; v.z += w.z; v.w += w.w;
    *(float4*)(hin + base) = v;
}

// ---------------------------------------------------------------- edge message + aggregate
// msg = relu(h_in[src] + edge_attr@We + be); atomicAdd into aggr[dst]
__global__ __launch_bounds__(256) void edge_kernel(
    const float* __restrict__ ea, const int* __restrict__ ei,
    const float* __restrict__ Wel, const float* __restrict__ bel,
    const float* __restrict__ hin, float* __restrict__ aggr, int ne)
{
    __shared__ float sW[EFEAT * DIM];
    __shared__ float sB[DIM];
    int tid = threadIdx.x;
    for (int i = tid; i < EFEAT * DIM; i += 256) sW[i] = Wel[i];
    if (tid < DIM) sB[tid] = bel[tid];
    __syncthreads();

    int e = blockIdx.x * 8 + (tid >> 5);
    if (e >= ne) return;
    int lane = tid & 31;
    int c0 = lane * 4;

    int src = ei[e];
    int dst = ei[ne + e];
    const float4 alo = *(const float4*)(ea + (size_t)e * EFEAT);
    const float4 ahi = *(const float4*)(ea + (size_t)e * EFEAT + 4);
    float ak[8] = {alo.x, alo.y, alo.z, alo.w, ahi.x, ahi.y, ahi.z, ahi.w};

    float4 acc = *(const float4*)(sB + c0);
    #pragma unroll
    for (int k = 0; k < 8; ++k) {
        const float4 w = *(const float4*)(sW + k * DIM + c0);
        acc.x = fmaf(ak[k], w.x, acc.x);
        acc.y = fmaf(ak[k], w.y, acc.y);
        acc.z = fmaf(ak[k], w.z, acc.z);
        acc.w = fmaf(ak[k], w.w, acc.w);
    }
    const float4 hv = *(const float4*)(hin + (size_t)src * DIM + c0);
    float m0 = fmaxf(hv.x + acc.x, 0.f);
    float m1 = fmaxf(hv.y + acc.y, 0.f);
    float m2 = fmaxf(hv.z + acc.z, 0.f);
    float m3 = fmaxf(hv.w + acc.w, 0.f);
    float* ap = aggr + (size_t)dst * DIM + c0;
    atomic_add_f(ap + 0, m0);
    atomic_add_f(ap + 1, m1);
    atomic_add_f(ap + 2, m2);
    atomic_add_f(ap + 3, m3);
}

// ---------------------------------------------------------------- fused GEMM
// C = act(A) @ B + bias ; epilogue accumulates per-column sum & sumsq (for BN)
// MODE 0: A = Aa + Ab (Ab may be null -> just Aa)
// MODE 1: A = relu(alpha[k]*Aa + beta[k]) with alpha/beta from (sSum,sSS,gA,btA,invCnt)
template <int MODE>
__global__ __launch_bounds__(256) void gemm_kernel(
    const float* __restrict__ Aa, const float* __restrict__ Ab,
    const float* __restrict__ sSum, const float* __restrict__ sSS,
    const float* __restrict__ gA, const float* __restrict__ btA, float invCnt,
    const float* __restrict__ B, const float* __restrict__ bias,
    float* __restrict__ Cout, float* __restrict__ outSum, float* __restrict__ outSS,
    int M, int K, int Nc)
{
    __shared__ float As[16][68];     // transposed A tile, padded (272B rows, 16B-aligned)
    __shared__ float Bs[16][64];
    __shared__ float alphaS[256], betaS[256];
    __shared__ float csum[64], css[64];

    const int tid = threadIdx.x;
    const int tx = tid & 15, ty = tid >> 4;
    const int row0 = blockIdx.x * 64, col0 = blockIdx.y * 64;

    if (tid < 64) { csum[tid] = 0.f; css[tid] = 0.f; }
    if (MODE == 1) {
        for (int k = tid; k < K; k += 256) {
            float m = sSum[k] * invCnt;
            float var = sSS[k] * invCnt - m * m;
            float r = rsqrtf(var + BN_EPS);
            float a = gA[k] * r;
            alphaS[k] = a;
            betaS[k] = btA[k] - m * a;
        }
    }
    __syncthreads();

    float acc[4][4];
    #pragma unroll
    for (int i = 0; i < 4; ++i)
        #pragma unroll
        for (int j = 0; j < 4; ++j) acc[i][j] = 0.f;

    const int lr = tid >> 2;        // 0..63 : A tile row
    const int lk = (tid & 3) * 4;   // A tile k offset
    const int bk = tid >> 4;        // 0..15 : B tile row
    const int bc = tx * 4;          // B tile col offset

    for (int kt = 0; kt < K; kt += 16) {
        int gr = row0 + lr;
        float4 va = make_float4(0.f, 0.f, 0.f, 0.f);
        if (gr < M) {
            va = *(const float4*)(Aa + (size_t)gr * K + kt + lk);
            if (MODE == 0 && Ab) {
                const float4 vb = *(const float4*)(Ab + (size_t)gr * K + kt + lk);
                va.x += vb.x; va.y += vb.y; va.z += vb.z; va.w += vb.w;
            }
            if (MODE == 1) {
                int k0 = kt + lk;
                va.x = fmaxf(fmaf(alphaS[k0 + 0], va.x, betaS[k0 + 0]), 0.f);
                va.y = fmaxf(fmaf(alphaS[k0 + 1], va.y, betaS[k0 + 1]), 0.f);
                va.z = fmaxf(fmaf(alphaS[k0 + 2], va.z, betaS[k0 + 2]), 0.f);
                va.w = fmaxf(fmaf(alphaS[k0 + 3], va.w, betaS[k0 + 3]), 0.f);
            }
        }
        As[lk + 0][lr] = va.x;
        As[lk + 1][lr] = va.y;
        As[lk + 2][lr] = va.z;
        As[lk + 3][lr] = va.w;
        const float4 vb4 = *(const float4*)(B + (size_t)(kt + bk) * Nc + col0 + bc);
        *(float4*)&Bs[bk][bc] = vb4;
        __syncthreads();
        #pragma unroll
        for (int kk = 0; kk < 16; ++kk) {
            const float4 a4 = *(const float4*)&As[kk][ty * 4];
            const float4 b4 = *(const float4*)&Bs[kk][tx * 4];
            float av[4] = {a4.x, a4.y, a4.z, a4.w};
            float bv4[4] = {b4.x, b4.y, b4.z, b4.w};
            #pragma unroll
            for (int i = 0; i < 4; ++i)
                #pragma unroll
                for (int j = 0; j < 4; ++j)
                    acc[i][j] = fmaf(av[i], bv4[j], acc[i][j]);
        }
        __syncthreads();
    }

    // epilogue: bias, store, per-column stats
    const float4 bvv = *(const float4*)(bias + col0 + tx * 4);
    float bias4[4] = {bvv.x, bvv.y, bvv.z, bvv.w};
    float ps[4] = {0.f, 0.f, 0.f, 0.f};
    float pq[4] = {0.f, 0.f, 0.f, 0.f};
    #pragma unroll
    for (int i = 0; i < 4; ++i) {
        int gr = row0 + ty * 4 + i;
        if (gr < M) {
            float o[4];
            #pragma unroll
            for (int j = 0; j < 4; ++j) {
                o[j] = acc[i][j] + bias4[j];
                ps[j] += o[j];
                pq[j] += o[j] * o[j];
            }
            float4 o4 = make_float4(o[0], o[1], o[2], o[3]);
            *(float4*)(Cout + (size_t)gr * Nc + col0 + tx * 4) = o4;
        }
    }
    #pragma unroll
    for (int j = 0; j < 4; ++j) {
        atomicAdd(&csum[tx * 4 + j], ps[j]);
        atomicAdd(&css[tx * 4 + j], pq[j]);
    }
    __syncthreads();
    if (tid < 64) {
        atomic_add_f(outSum + col0 + tid, csum[tid]);
        atomic_add_f(outSS + col0 + tid, css[tid]);
    }
}

// ---------------------------------------------------------------- pooled += segment_sum(h_in, batch)
__global__ __launch_bounds__(256) void pooled_scatter_kernel(
    const float* __restrict__ hin, const int* __restrict__ batch,
    float* __restrict__ pooled, int total4)
{
    int idx = blockIdx.x * 256 + threadIdx.x;
    if (idx >= total4) return;
    int base = idx * 4;
    int n = base >> 7;
    int c = base & (DIM - 1);
    int grp = batch[n];
    const float4 v = *(const float4*)(hin + base);
    float* pp = pooled + (size_t)grp * DIM + c;
    atomic_add_f(pp + 0, v.x);
    atomic_add_f(pp + 1, v.y);
    atomic_add_f(pp + 2, v.z);
    atomic_add_f(pp + 3, v.w);
}

// ---------------------------------------------------------------- vn = relu(bn(vnpre))
__global__ void vn_apply_kernel(
    const float* __restrict__ vnpre, const float* __restrict__ vsum, const float* __restrict__ vss,
    const float* __restrict__ g, const float* __restrict__ b, float invG, float* __restrict__ vn)
{
    int idx = blockIdx.x * 256 + threadIdx.x;
    int total4 = N_GRAPH * DIM / 4;
    if (idx >= total4) return;
    int base = idx * 4;
    int c = base & (DIM - 1);
    float4 v = *(const float4*)(vnpre + base);
    float o[4] = {v.x, v.y, v.z, v.w};
    #pragma unroll
    for (int j = 0; j < 4; ++j) {
        int cj = c + j;
        float m = vsum[cj] * invG;
        float var = vss[cj] * invG - m * m;
        float r = rsqrtf(var + BN_EPS);
        float a = g[cj] * r;
        o[j] = fmaxf(fmaf(a, o[j], b[cj] - m * a), 0.f);
    }
    *(float4*)(vn + base) = make_float4(o[0], o[1], o[2], o[3]);
}

// ---------------------------------------------------------------- final in-place BN on d_out (no relu)
__global__ __launch_bounds__(256) void final_bn_kernel(
    float* __restrict__ outp, const float* __restrict__ sum2, const float* __restrict__ ss2,
    const float* __restrict__ g, const float* __restrict__ b, float invN, int total4)
{
    int idx = blockIdx.x * 256 + threadIdx.x;
    if (idx >= total4) return;
    int base = idx * 4;
    int c = base & (DIM - 1);
    float4 v = *(const float4*)(outp + base);
    float o[4] = {v.x, v.y, v.z, v.w};
    #pragma unroll
    for (int j = 0; j < 4; ++j) {
        int cj = c + j;
        float m = sum2[cj] * invN;
        float var = ss2[cj] * invN - m * m;
        float r = rsqrtf(var + BN_EPS);
        float a = g[cj] * r;
        o[j] = fmaf(a, o[j], b[cj] - m * a);
    }
    *(float4*)(outp + base) = make_float4(o[0], o[1], o[2], o[3]);
}

// ---------------------------------------------------------------- launch
extern "C" void kernel_launch(void* const* d_in, const int* in_sizes, int n_in,
                              void* d_out, int out_size, void* d_ws, size_t ws_size,
                              hipStream_t stream) {
    const float* x         = (const float*)d_in[0];
    const float* edge_attr = (const float*)d_in[1];
    const float* vn_emb    = (const float*)d_in[2];
    const float* We        = (const float*)d_in[3];
    const float* be        = (const float*)d_in[4];
    const float* W1        = (const float*)d_in[5];
    const float* b1        = (const float*)d_in[6];
    const float* g1v       = (const float*)d_in[7];
    const float* bt1       = (const float*)d_in[8];
    const float* W2        = (const float*)d_in[9];
    const float* b2        = (const float*)d_in[10];
    const float* gb        = (const float*)d_in[11];
    const float* bb        = (const float*)d_in[12];
    const float* Wv1       = (const float*)d_in[13];
    const float* bv1       = (const float*)d_in[14];
    const float* gv1       = (const float*)d_in[15];
    const float* btv1      = (const float*)d_in[16];
    const float* Wv2       = (const float*)d_in[17];
    const float* bv2       = (const float*)d_in[18];
    const float* gv2       = (const float*)d_in[19];
    const float* btv2      = (const float*)d_in[20];
    const int* edge_index  = (const int*)d_in[21];
    const int* batch       = (const int*)d_in[22];
    float* outp = (float*)d_out;

    float* ws     = (float*)d_ws;
    float* h_in   = ws;
    float* aggr   = h_in + (size_t)N_NODES * DIM;
    float* c1     = aggr + (size_t)N_NODES * DIM;
    float* vn     = c1 + (size_t)N_NODES * HID;
    float* pooled = vn + N_GRAPH * DIM;
    float* tpre   = pooled + N_GRAPH * DIM;
    float* vnpre  = tpre + N_GRAPH * HID;
    float* stats  = vnpre + N_GRAPH * DIM;
    float* sum1 = stats,        *ss1 = stats + 256;
    float* sum2 = stats + 512,  *ss2 = stats + 640;
    float* vsum1 = stats + 768, *vss1 = stats + 1024;
    float* vsum2 = stats + 1280, *vss2 = stats + 1408;

    const float invN = 1.0f / (float)N_NODES;
    const float invG = 1.0f / (float)N_GRAPH;
    const int total4 = N_NODES * DIM / 4;

    init_vn_kernel<<<(N_GRAPH * DIM + 255) / 256, 256, 0, stream>>>(vn_emb, vn);

    for (int l = 0; l < N_LAYER; ++l) {
        // h_in = act(h_prev) + vn[batch]   (reads prev layer's stats BEFORE zeroing)
        if (l == 0)
            hin_kernel<false><<<(total4 + 255) / 256, 256, 0, stream>>>(
                x, nullptr, nullptr, nullptr, nullptr, 0.f, batch, vn, h_in, total4);
        else
            hin_kernel<true><<<(total4 + 255) / 256, 256, 0, stream>>>(
                outp, sum2, ss2, gb + (size_t)(l - 1) * DIM, bb + (size_t)(l - 1) * DIM,
                invN, batch, vn, h_in, total4);

        hipMemsetAsync(aggr, 0, (size_t)N_NODES * DIM * sizeof(float), stream);
        hipMemsetAsync(stats, 0, 2048 * sizeof(float), stream);
        if (l < N_LAYER - 1)
            hipMemsetAsync(pooled, 0, (size_t)N_GRAPH * DIM * sizeof(float), stream);

        edge_kernel<<<(N_EDGES + 7) / 8, 256, 0, stream>>>(
            edge_attr, edge_index, We + (size_t)l * EFEAT * DIM, be + (size_t)l * DIM,
            h_in, aggr, N_EDGES);

        dim3 g1d((N_NODES + 63) / 64, HID / 64);
        gemm_kernel<0><<<g1d, 256, 0, stream>>>(
            h_in, aggr, nullptr, nullptr, nullptr, nullptr, 0.f,
            W1 + (size_t)l * DIM * HID, b1 + (size_t)l * HID,
            c1, sum1, ss1, N_NODES, DIM, HID);

        dim3 g2d((N_NODES + 63) / 64, DIM / 64);
        gemm_kernel<1><<<g2d, 256, 0, stream>>>(
            c1, nullptr, sum1, ss1, g1v + (size_t)l * HID, bt1 + (size_t)l * HID, invN,
            W2 + (size_t)l * HID * DIM, b2 + (size_t)l * DIM,
            outp, sum2, ss2, N_NODES, HID, DIM);

        if (l < N_LAYER - 1) {
            pooled_scatter_kernel<<<(total4 + 255) / 256, 256, 0, stream>>>(
                h_in, batch, pooled, total4);

            dim3 g3d(N_GRAPH / 64, HID / 64);
            gemm_kernel<0><<<g3d, 256, 0, stream>>>(
                pooled, vn, nullptr, nullptr, nullptr, nullptr, 0.f,
                Wv1 + (size_t)l * DIM * HID, bv1 + (size_t)l * HID,
                tpre, vsum1, vss1, N_GRAPH, DIM, HID);

            dim3 g4d(N_GRAPH / 64, DIM / 64);
            gemm_kernel<1><<<g4d, 256, 0, stream>>>(
                tpre, nullptr, vsum1, vss1, gv1 + (size_t)l * HID, btv1 + (size_t)l * HID, invG,
                Wv2 + (size_t)l * HID * DIM, bv2 + (size_t)l * DIM,
                vnpre, vsum2, vss2, N_GRAPH, HID, DIM);

            vn_apply_kernel<<<(N_GRAPH * DIM / 4 + 255) / 256, 256, 0, stream>>>(
                vnpre, vsum2, vss2, gv2 + (size_t)l * DIM, btv2 + (size_t)l * DIM, invG, vn);
        }
    }

    final_bn_kernel<<<(total4 + 255) / 256, 256, 0, stream>>>(
        outp, sum2, ss2, gb + (size_t)2 * DIM, bb + (size_t)2 * DIM, invN, total4);
}

// Round 2
// 1362.971 us; speedup vs baseline: 3.7555x; 3.7555x over previous
//
#include <hip/hip_runtime.h>
#include <hip/hip_bf16.h>

#define N_NODES 50000
#define N_EDGES 800000
#define DIM 128
#define HID 256
#define N_GRAPH 512
#define N_LAYER 3
#define EFEAT 8
#define BN_EPS 1e-5f

// ---------------------------------------------------------------- utilities

__device__ __forceinline__ void atomic_add_f(float* p, float v) {
    unsafeAtomicAdd(p, v);   // global_atomic_add_f32 (only used for tiny stats now)
}

// ---------------------------------------------------------------- init vn
__global__ void init_vn_kernel(const float* __restrict__ vn_emb, float* __restrict__ vn) {
    int idx = blockIdx.x * 256 + threadIdx.x;
    if (idx < N_GRAPH * DIM) vn[idx] = vn_emb[idx & (DIM - 1)];
}

// ---------------------------------------------------------------- CSR build
__global__ __launch_bounds__(256) void hist_kernel(const int* __restrict__ ei, int* __restrict__ deg) {
    int e = blockIdx.x * 256 + threadIdx.x;
    if (e < N_EDGES) atomicAdd(&deg[ei[N_EDGES + e]], 1);
}

// single-block exclusive scan of deg[0..N_NODES) -> rowptr[0..N_NODES]
__global__ __launch_bounds__(1024) void scan_kernel(const int* __restrict__ deg, int* __restrict__ rowptr) {
    __shared__ int wsum[16];
    __shared__ int carry;
    int tid = threadIdx.x;
    if (tid == 0) { carry = 0; rowptr[0] = 0; }
    __syncthreads();
    for (int base = 0; base < N_NODES; base += 1024) {
        int i = base + tid;
        int v = (i < N_NODES) ? deg[i] : 0;
        int lane = tid & 63, w = tid >> 6;
        int s = v;
        #pragma unroll
        for (int d = 1; d < 64; d <<= 1) { int t = __shfl_up(s, d); if (lane >= d) s += t; }
        if (lane == 63) wsum[w] = s;
        __syncthreads();
        if (tid < 64) {
            int t = (tid < 16) ? wsum[tid] : 0;
            #pragma unroll
            for (int d = 1; d < 16; d <<= 1) { int u = __shfl_up(t, d); if (tid >= d) t += u; }
            if (tid < 16) wsum[tid] = t;
        }
        __syncthreads();
        int excl = (w > 0) ? wsum[w - 1] : 0;
        int incl = s + excl + carry;
        if (i < N_NODES) rowptr[i + 1] = incl;
        __syncthreads();
        if (tid == 0) carry += wsum[15];
        __syncthreads();
    }
}

__global__ __launch_bounds__(256) void scatter_kernel(
    const int* __restrict__ ei, const int* __restrict__ rowptr,
    int* __restrict__ cursor, int2* __restrict__ sE)
{
    int e = blockIdx.x * 256 + threadIdx.x;
    if (e >= N_EDGES) return;
    int dst = ei[N_EDGES + e];
    int p = atomicAdd(&cursor[dst], 1);
    sE[rowptr[dst] + p] = make_int2(ei[e], e);
}

// ---------------------------------------------------------------- h_in = act(src) + vn[batch]
template <bool USEBN>
__global__ __launch_bounds__(256) void hin_kernel(
    const float* __restrict__ src,
    const float* __restrict__ sum2, const float* __restrict__ ss2,
    const float* __restrict__ g, const float* __restrict__ b, float invN,
    const int* __restrict__ batch, const float* __restrict__ vn,
    float* __restrict__ hin, int total4)
{
    int idx = blockIdx.x * 256 + threadIdx.x;
    if (idx >= total4) return;
    int base = idx * 4;
    int n = base >> 7;
    int c = base & (DIM - 1);
    float4 v = *(const float4*)(src + base);
    if (USEBN) {
        float o[4] = {v.x, v.y, v.z, v.w};
        #pragma unroll
        for (int j = 0; j < 4; ++j) {
            int cj = c + j;
            float m = sum2[cj] * invN;
            float var = ss2[cj] * invN - m * m;
            float r = rsqrtf(var + BN_EPS);
            float a = g[cj] * r;
            o[j] = fmaxf(fmaf(a, o[j], b[cj] - m * a), 0.f);
        }
        v.x = o[0]; v.y = o[1]; v.z = o[2]; v.w = o[3];
    }
    int grp = batch[n];
    const float4 w = *(const float4*)(vn + grp * DIM + c);
    v.x += w.x; v.y += w.y; v.z += w.z; v.w += w.w;
    *(float4*)(hin + base) = v;
}

// ---------------------------------------------------------------- gather aggregation
// z[n] = h_in[n] + sum_{e: dst=n} relu(h_in[src_e] + ea[e]@We + be)
// one wave per node; 2 dims per lane; We held in registers (16 VGPRs)
__global__ __launch_bounds__(256) void aggr_kernel(
    const int* __restrict__ rowptr, const int2* __restrict__ sE,
    const float* __restrict__ ea,
    const float* __restrict__ Wel, const float* __restrict__ bel,
    const float* __restrict__ hin, float* __restrict__ z)
{
    int node = blockIdx.x * 4 + (threadIdx.x >> 6);
    if (node >= N_NODES) return;
    int lane = threadIdx.x & 63;
    int c = lane * 2;

    float2 rW[EFEAT];
    #pragma unroll
    for (int k = 0; k < EFEAT; ++k)
        rW[k] = *(const float2*)(Wel + k * DIM + c);
    const float2 rB = *(const float2*)(bel + c);

    float2 acc = *(const float2*)(hin + (size_t)node * DIM + c);
    int beg = rowptr[node], end = rowptr[node + 1];

    int i = beg;
    for (; i + 1 < end; i += 2) {
        int2 s0 = sE[i];
        int2 s1 = sE[i + 1];
        const float2 h0 = *(const float2*)(hin + (size_t)s0.x * DIM + c);
        const float2 h1 = *(const float2*)(hin + (size_t)s1.x * DIM + c);
        const float4 a0l = *(const float4*)(ea + (size_t)s0.y * EFEAT);
        const float4 a0h = *(const float4*)(ea + (size_t)s0.y * EFEAT + 4);
        const float4 a1l = *(const float4*)(ea + (size_t)s1.y * EFEAT);
        const float4 a1h = *(const float4*)(ea + (size_t)s1.y * EFEAT + 4);
        float ak0[8] = {a0l.x, a0l.y, a0l.z, a0l.w, a0h.x, a0h.y, a0h.z, a0h.w};
        float ak1[8] = {a1l.x, a1l.y, a1l.z, a1l.w, a1h.x, a1h.y, a1h.z, a1h.w};
        float e0x = rB.x, e0y = rB.y, e1x = rB.x, e1y = rB.y;
        #pragma unroll
        for (int k = 0; k < EFEAT; ++k) {
            e0x = fmaf(ak0[k], rW[k].x, e0x);
            e0y = fmaf(ak0[k], rW[k].y, e0y);
            e1x = fmaf(ak1[k], rW[k].x, e1x);
            e1y = fmaf(ak1[k], rW[k].y, e1y);
        }
        acc.x += fmaxf(h0.x + e0x, 0.f) + fmaxf(h1.x + e1x, 0.f);
        acc.y += fmaxf(h0.y + e0y, 0.f) + fmaxf(h1.y + e1y, 0.f);
    }
    if (i < end) {
        int2 s0 = sE[i];
        const float2 h0 = *(const float2*)(hin + (size_t)s0.x * DIM + c);
        const float4 a0l = *(const float4*)(ea + (size_t)s0.y * EFEAT);
        const float4 a0h = *(const float4*)(ea + (size_t)s0.y * EFEAT + 4);
        float ak0[8] = {a0l.x, a0l.y, a0l.z, a0l.w, a0h.x, a0h.y, a0h.z, a0h.w};
        float e0x = rB.x, e0y = rB.y;
        #pragma unroll
        for (int k = 0; k < EFEAT; ++k) {
            e0x = fmaf(ak0[k], rW[k].x, e0x);
            e0y = fmaf(ak0[k], rW[k].y, e0y);
        }
        acc.x += fmaxf(h0.x + e0x, 0.f);
        acc.y += fmaxf(h0.y + e0y, 0.f);
    }
    *(float2*)(z + (size_t)node * DIM + c) = acc;
}

// ---------------------------------------------------------------- fused GEMM
// C = act(A) @ B + bias ; epilogue accumulates per-column sum & sumsq (for BN)
// MODE 0: A = Aa
// MODE 1: A = relu(alpha[k]*Aa + beta[k]) with alpha/beta from (sSum,sSS,gA,btA,invCnt)
template <int MODE>
__global__ __launch_bounds__(256) void gemm_kernel(
    const float* __restrict__ Aa,
    const float* __restrict__ sSum, const float* __restrict__ sSS,
    const float* __restrict__ gA, const float* __restrict__ btA, float invCnt,
    const float* __restrict__ B, const float* __restrict__ bias,
    float* __restrict__ Cout, float* __restrict__ outSum, float* __restrict__ outSS,
    int M, int K, int Nc)
{
    __shared__ float As[16][68];
    __shared__ float Bs[16][64];
    __shared__ float alphaS[256], betaS[256];
    __shared__ float csum[64], css[64];

    const int tid = threadIdx.x;
    const int tx = tid & 15, ty = tid >> 4;
    const int row0 = blockIdx.x * 64, col0 = blockIdx.y * 64;

    if (tid < 64) { csum[tid] = 0.f; css[tid] = 0.f; }
    if (MODE == 1) {
        for (int k = tid; k < K; k += 256) {
            float m = sSum[k] * invCnt;
            float var = sSS[k] * invCnt - m * m;
            float r = rsqrtf(var + BN_EPS);
            float a = gA[k] * r;
            alphaS[k] = a;
            betaS[k] = btA[k] - m * a;
        }
    }
    __syncthreads();

    float acc[4][4];
    #pragma unroll
    for (int i = 0; i < 4; ++i)
        #pragma unroll
        for (int j = 0; j < 4; ++j) acc[i][j] = 0.f;

    const int lr = tid >> 2;
    const int lk = (tid & 3) * 4;
    const int bk = tid >> 4;
    const int bc = tx * 4;

    for (int kt = 0; kt < K; kt += 16) {
        int gr = row0 + lr;
        float4 va = make_float4(0.f, 0.f, 0.f, 0.f);
        if (gr < M) {
            va = *(const float4*)(Aa + (size_t)gr * K + kt + lk);
            if (MODE == 1) {
                int k0 = kt + lk;
                va.x = fmaxf(fmaf(alphaS[k0 + 0], va.x, betaS[k0 + 0]), 0.f);
                va.y = fmaxf(fmaf(alphaS[k0 + 1], va.y, betaS[k0 + 1]), 0.f);
                va.z = fmaxf(fmaf(alphaS[k0 + 2], va.z, betaS[k0 + 2]), 0.f);
                va.w = fmaxf(fmaf(alphaS[k0 + 3], va.w, betaS[k0 + 3]), 0.f);
            }
        }
        As[lk + 0][lr] = va.x;
        As[lk + 1][lr] = va.y;
        As[lk + 2][lr] = va.z;
        As[lk + 3][lr] = va.w;
        const float4 vb4 = *(const float4*)(B + (size_t)(kt + bk) * Nc + col0 + bc);
        *(float4*)&Bs[bk][bc] = vb4;
        __syncthreads();
        #pragma unroll
        for (int kk = 0; kk < 16; ++kk) {
            const float4 a4 = *(const float4*)&As[kk][ty * 4];
            const float4 b4 = *(const float4*)&Bs[kk][tx * 4];
            float av[4] = {a4.x, a4.y, a4.z, a4.w};
            float bv4[4] = {b4.x, b4.y, b4.z, b4.w};
            #pragma unroll
            for (int i = 0; i < 4; ++i)
                #pragma unroll
                for (int j = 0; j < 4; ++j)
                    acc[i][j] = fmaf(av[i], bv4[j], acc[i][j]);
        }
        __syncthreads();
    }

    const float4 bvv = *(const float4*)(bias + col0 + tx * 4);
    float bias4[4] = {bvv.x, bvv.y, bvv.z, bvv.w};
    float ps[4] = {0.f, 0.f, 0.f, 0.f};
    float pq[4] = {0.f, 0.f, 0.f, 0.f};
    #pragma unroll
    for (int i = 0; i < 4; ++i) {
        int gr = row0 + ty * 4 + i;
        if (gr < M) {
            float o[4];
            #pragma unroll
            for (int j = 0; j < 4; ++j) {
                o[j] = acc[i][j] + bias4[j];
                ps[j] += o[j];
                pq[j] += o[j] * o[j];
            }
            *(float4*)(Cout + (size_t)gr * Nc + col0 + tx * 4) = make_float4(o[0], o[1], o[2], o[3]);
        }
    }
    #pragma unroll
    for (int j = 0; j < 4; ++j) {
        atomicAdd(&csum[tx * 4 + j], ps[j]);
        atomicAdd(&css[tx * 4 + j], pq[j]);
    }
    __syncthreads();
    if (tid < 64) {
        atomic_add_f(outSum + col0 + tid, csum[tid]);
        atomic_add_f(outSS + col0 + tid, css[tid]);
    }
}

// ---------------------------------------------------------------- pooled[g] = vn[g] + segment_sum(h_in, batch)[g]
// batch is sorted: binary-search the graph's node range; one block per graph
__global__ __launch_bounds__(128) void pooled_seg_kernel(
    const float* __restrict__ hin, const int* __restrict__ batch,
    const float* __restrict__ vn, float* __restrict__ pooled)
{
    int g = blockIdx.x;
    int c = threadIdx.x;
    int lo = 0, hi = N_NODES;
    while (lo < hi) { int mid = (lo + hi) >> 1; if (batch[mid] < g) lo = mid + 1; else hi = mid; }
    int start = lo;
    hi = N_NODES;
    while (lo < hi) { int mid = (lo + hi) >> 1; if (batch[mid] < g + 1) lo = mid + 1; else hi = mid; }
    int end = lo;
    float acc = vn[g * DIM + c];
    for (int n = start; n < end; ++n) acc += hin[(size_t)n * DIM + c];
    pooled[g * DIM + c] = acc;
}

// ---------------------------------------------------------------- vn = relu(bn(vnpre))
__global__ void vn_apply_kernel(
    const float* __restrict__ vnpre, const float* __restrict__ vsum, const float* __restrict__ vss,
    const float* __restrict__ g, const float* __restrict__ b, float invG, float* __restrict__ vn)
{
    int idx = blockIdx.x * 256 + threadIdx.x;
    int total4 = N_GRAPH * DIM / 4;
    if (idx >= total4) return;
    int base = idx * 4;
    int c = base & (DIM - 1);
    float4 v = *(const float4*)(vnpre + base);
    float o[4] = {v.x, v.y, v.z, v.w};
    #pragma unroll
    for (int j = 0; j < 4; ++j) {
        int cj = c + j;
        float m = vsum[cj] * invG;
        float var = vss[cj] * invG - m * m;
        float r = rsqrtf(var + BN_EPS);
        float a = g[cj] * r;
        o[j] = fmaxf(fmaf(a, o[j], b[cj] - m * a), 0.f);
    }
    *(float4*)(vn + base) = make_float4(o[0], o[1], o[2], o[3]);
}

// ---------------------------------------------------------------- final in-place BN on d_out (no relu)
__global__ __launch_bounds__(256) void final_bn_kernel(
    float* __restrict__ outp, const float* __restrict__ sum2, const float* __restrict__ ss2,
    const float* __restrict__ g, const float* __restrict__ b, float invN, int total4)
{
    int idx = blockIdx.x * 256 + threadIdx.x;
    if (idx >= total4) return;
    int base = idx * 4;
    int c = base & (DIM - 1);
    float4 v = *(const float4*)(outp + base);
    float o[4] = {v.x, v.y, v.z, v.w};
    #pragma unroll
    for (int j = 0; j < 4; ++j) {
        int cj = c + j;
        float m = sum2[cj] * invN;
        float var = ss2[cj] * invN - m * m;
        float r = rsqrtf(var + BN_EPS);
        float a = g[cj] * r;
        o[j] = fmaf(a, o[j], b[cj] - m * a);
    }
    *(float4*)(outp + base) = make_float4(o[0], o[1], o[2], o[3]);
}

// ---------------------------------------------------------------- launch
extern "C" void kernel_launch(void* const* d_in, const int* in_sizes, int n_in,
                              void* d_out, int out_size, void* d_ws, size_t ws_size,
                              hipStream_t stream) {
    const float* x         = (const float*)d_in[0];
    const float* edge_attr = (const float*)d_in[1];
    const float* vn_emb    = (const float*)d_in[2];
    const float* We        = (const float*)d_in[3];
    const float* be        = (const float*)d_in[4];
    const float* W1        = (const float*)d_in[5];
    const float* b1        = (const float*)d_in[6];
    const float* g1v       = (const float*)d_in[7];
    const float* bt1       = (const float*)d_in[8];
    const float* W2        = (const float*)d_in[9];
    const float* b2        = (const float*)d_in[10];
    const float* gb        = (const float*)d_in[11];
    const float* bb        = (const float*)d_in[12];
    const float* Wv1       = (const float*)d_in[13];
    const float* bv1       = (const float*)d_in[14];
    const float* gv1       = (const float*)d_in[15];
    const float* btv1      = (const float*)d_in[16];
    const float* Wv2       = (const float*)d_in[17];
    const float* bv2       = (const float*)d_in[18];
    const float* gv2       = (const float*)d_in[19];
    const float* btv2      = (const float*)d_in[20];
    const int* edge_index  = (const int*)d_in[21];
    const int* batch       = (const int*)d_in[22];
    float* outp = (float*)d_out;

    float* ws     = (float*)d_ws;
    float* h_in   = ws;                                        // 6.4M
    float* z      = h_in + (size_t)N_NODES * DIM;              // 6.4M
    float* c1     = z + (size_t)N_NODES * DIM;                 // 12.8M
    float* vn     = c1 + (size_t)N_NODES * HID;
    float* pooled = vn + N_GRAPH * DIM;
    float* tpre   = pooled + N_GRAPH * DIM;
    float* vnpre  = tpre + N_GRAPH * HID;
    float* stats  = vnpre + N_GRAPH * DIM;                     // 2048 floats
    float* sum1 = stats,        *ss1 = stats + 256;
    float* sum2 = stats + 512,  *ss2 = stats + 640;
    float* vsum1 = stats + 768, *vss1 = stats + 1024;
    float* vsum2 = stats + 1280, *vss2 = stats + 1408;
    int* rowptr = (int*)(stats + 2048);                        // N_NODES+1
    int* cursor = rowptr + (N_NODES + 1);                      // N_NODES
    int2* sE    = (int2*)(cursor + N_NODES + 3);               // N_EDGES, 8B-aligned

    const float invN = 1.0f / (float)N_NODES;
    const float invG = 1.0f / (float)N_GRAPH;
    const int total4 = N_NODES * DIM / 4;

    // ---- CSR build (edge_index constant across layers) ----
    hipMemsetAsync(cursor, 0, N_NODES * sizeof(int), stream);
    hist_kernel<<<(N_EDGES + 255) / 256, 256, 0, stream>>>(edge_index, cursor);
    scan_kernel<<<1, 1024, 0, stream>>>(cursor, rowptr);
    hipMemsetAsync(cursor, 0, N_NODES * sizeof(int), stream);
    scatter_kernel<<<(N_EDGES + 255) / 256, 256, 0, stream>>>(edge_index, rowptr, cursor, sE);

    init_vn_kernel<<<(N_GRAPH * DIM + 255) / 256, 256, 0, stream>>>(vn_emb, vn);

    for (int l = 0; l < N_LAYER; ++l) {
        if (l == 0)
            hin_kernel<false><<<(total4 + 255) / 256, 256, 0, stream>>>(
                x, nullptr, nullptr, nullptr, nullptr, 0.f, batch, vn, h_in, total4);
        else
            hin_kernel<true><<<(total4 + 255) / 256, 256, 0, stream>>>(
                outp, sum2, ss2, gb + (size_t)(l - 1) * DIM, bb + (size_t)(l - 1) * DIM,
                invN, batch, vn, h_in, total4);

        hipMemsetAsync(stats, 0, 2048 * sizeof(float), stream);

        aggr_kernel<<<(N_NODES + 3) / 4, 256, 0, stream>>>(
            rowptr, sE, edge_attr, We + (size_t)l * EFEAT * DIM, be + (size_t)l * DIM,
            h_in, z);

        dim3 g1d((N_NODES + 63) / 64, HID / 64);
        gemm_kernel<0><<<g1d, 256, 0, stream>>>(
            z, nullptr, nullptr, nullptr, nullptr, 0.f,
            W1 + (size_t)l * DIM * HID, b1 + (size_t)l * HID,
            c1, sum1, ss1, N_NODES, DIM, HID);

        dim3 g2d((N_NODES + 63) / 64, DIM / 64);
        gemm_kernel<1><<<g2d, 256, 0, stream>>>(
            c1, sum1, ss1, g1v + (size_t)l * HID, bt1 + (size_t)l * HID, invN,
            W2 + (size_t)l * HID * DIM, b2 + (size_t)l * DIM,
            outp, sum2, ss2, N_NODES, HID, DIM);

        if (l < N_LAYER - 1) {
            pooled_seg_kernel<<<N_GRAPH, 128, 0, stream>>>(h_in, batch, vn, pooled);

            dim3 g3d(N_GRAPH / 64, HID / 64);
            gemm_kernel<0><<<g3d, 256, 0, stream>>>(
                pooled, nullptr, nullptr, nullptr, nullptr, 0.f,
                Wv1 + (size_t)l * DIM * HID, bv1 + (size_t)l * HID,
                tpre, vsum1, vss1, N_GRAPH, DIM, HID);

            dim3 g4d(N_GRAPH / 64, DIM / 64);
            gemm_kernel<1><<<g4d, 256, 0, stream>>>(
                tpre, vsum1, vss1, gv1 + (size_t)l * HID, btv1 + (size_t)l * HID, invG,
                Wv2 + (size_t)l * HID * DIM, bv2 + (size_t)l * DIM,
                vnpre, vsum2, vss2, N_GRAPH, HID, DIM);

            vn_apply_kernel<<<(N_GRAPH * DIM / 4 + 255) / 256, 256, 0, stream>>>(
                vnpre, vsum2, vss2, gv2 + (size_t)l * DIM, btv2 + (size_t)l * DIM, invG, vn);
        }
    }

    final_bn_kernel<<<(total4 + 255) / 256, 256, 0, stream>>>(
        outp, sum2, ss2, gb + (size_t)2 * DIM, bb + (size_t)2 * DIM, invN, total4);
}

// Round 3
// 987.098 us; speedup vs baseline: 5.1855x; 1.3808x over previous
//
#include <hip/hip_runtime.h>
#include <hip/hip_bf16.h>

#define N_NODES 50000
#define N_EDGES 800000
#define DIM 128
#define HID 256
#define N_GRAPH 512
#define N_LAYER 3
#define EFEAT 8
#define BN_EPS 1e-5f

typedef unsigned short u16;
typedef unsigned int u32;

using bf16x8_t = short __attribute__((ext_vector_type(8)));
using f32x4_t  = float __attribute__((ext_vector_type(4)));

// ---------------------------------------------------------------- utilities

__device__ __forceinline__ void atomic_add_f(float* p, float v) {
    unsafeAtomicAdd(p, v);
}
__device__ __forceinline__ u16 f2bf(float x) {
    union { float f; u32 u; } v; v.f = x;
    u32 r = v.u + 0x7FFF + ((v.u >> 16) & 1);
    return (u16)(r >> 16);
}
__device__ __forceinline__ float bf2f(u16 u) {
    union { u32 i; float f; } v; v.i = (u32)u << 16; return v.f;
}
__device__ __forceinline__ float2 up2(u32 p) {
    return make_float2(bf2f((u16)(p & 0xFFFF)), bf2f((u16)(p >> 16)));
}
__device__ __forceinline__ u32 pk2(float a, float b) {
    return (u32)f2bf(a) | ((u32)f2bf(b) << 16);
}

// ---------------------------------------------------------------- init vn
__global__ void init_vn_kernel(const float* __restrict__ vn_emb, float* __restrict__ vn) {
    int idx = blockIdx.x * 256 + threadIdx.x;
    if (idx < N_GRAPH * DIM) vn[idx] = vn_emb[idx & (DIM - 1)];
}

// ---------------------------------------------------------------- weight transpose+convert to bf16
// W1 [3][128][256] -> W1t [3][256][128] ; W2 [3][256][128] -> W2t [3][128][256]
__global__ __launch_bounds__(256) void wconv_kernel(
    const float* __restrict__ W1, const float* __restrict__ W2,
    u16* __restrict__ W1t, u16* __restrict__ W2t)
{
    int idx = blockIdx.x * 256 + threadIdx.x;
    if (idx >= 6 * 32768) return;
    int m = idx >> 15;      // 0..5
    int off = idx & 32767;
    int l = m >> 1;
    if ((m & 1) == 0) {
        int r = off >> 8, c = off & 255;   // W1 row-major [128][256]
        W1t[(size_t)l * 32768 + c * 128 + r] = f2bf(W1[(size_t)l * 32768 + r * 256 + c]);
    } else {
        int r = off >> 7, c = off & 127;   // W2 row-major [256][128]
        W2t[(size_t)l * 32768 + c * 256 + r] = f2bf(W2[(size_t)l * 32768 + r * 128 + c]);
    }
}

// ---------------------------------------------------------------- CSR build
__global__ __launch_bounds__(256) void hist_kernel(const int* __restrict__ ei, int* __restrict__ deg) {
    int e = blockIdx.x * 256 + threadIdx.x;
    if (e < N_EDGES) atomicAdd(&deg[ei[N_EDGES + e]], 1);
}

__global__ __launch_bounds__(1024) void scan_kernel(const int* __restrict__ deg, int* __restrict__ rowptr) {
    __shared__ int wsum[16];
    __shared__ int carry;
    int tid = threadIdx.x;
    if (tid == 0) { carry = 0; rowptr[0] = 0; }
    __syncthreads();
    for (int base = 0; base < N_NODES; base += 1024) {
        int i = base + tid;
        int v = (i < N_NODES) ? deg[i] : 0;
        int lane = tid & 63, w = tid >> 6;
        int s = v;
        #pragma unroll
        for (int d = 1; d < 64; d <<= 1) { int t = __shfl_up(s, d); if (lane >= d) s += t; }
        if (lane == 63) wsum[w] = s;
        __syncthreads();
        if (tid < 64) {
            int t = (tid < 16) ? wsum[tid] : 0;
            #pragma unroll
            for (int d = 1; d < 16; d <<= 1) { int u = __shfl_up(t, d); if (tid >= d) t += u; }
            if (tid < 16) wsum[tid] = t;
        }
        __syncthreads();
        int excl = (w > 0) ? wsum[w - 1] : 0;
        int incl = s + excl + carry;
        if (i < N_NODES) rowptr[i + 1] = incl;
        __syncthreads();
        if (tid == 0) carry += wsum[15];
        __syncthreads();
    }
}

__global__ __launch_bounds__(256) void scatter_kernel(
    const int* __restrict__ ei, const int* __restrict__ rowptr,
    int* __restrict__ cursor, int2* __restrict__ sE)
{
    int e = blockIdx.x * 256 + threadIdx.x;
    if (e >= N_EDGES) return;
    int dst = ei[N_EDGES + e];
    int p = atomicAdd(&cursor[dst], 1);
    sE[rowptr[dst] + p] = make_int2(ei[e], e);
}

// ---------------------------------------------------------------- h_in = act(src) + vn[batch]  (bf16 out)
template <bool USEBN>
__global__ __launch_bounds__(256) void hin_kernel(
    const float* __restrict__ src,
    const float* __restrict__ sum2, const float* __restrict__ ss2,
    const float* __restrict__ g, const float* __restrict__ b, float invN,
    const int* __restrict__ batch, const float* __restrict__ vn,
    u16* __restrict__ hin, int total4)
{
    int idx = blockIdx.x * 256 + threadIdx.x;
    if (idx >= total4) return;
    int base = idx * 4;
    int n = base >> 7;
    int c = base & (DIM - 1);
    float4 v = *(const float4*)(src + base);
    float o[4] = {v.x, v.y, v.z, v.w};
    if (USEBN) {
        #pragma unroll
        for (int j = 0; j < 4; ++j) {
            int cj = c + j;
            float m = sum2[cj] * invN;
            float var = ss2[cj] * invN - m * m;
            float r = rsqrtf(var + BN_EPS);
            float a = g[cj] * r;
            o[j] = fmaxf(fmaf(a, o[j], b[cj] - m * a), 0.f);
        }
    }
    int grp = batch[n];
    const float4 w = *(const float4*)(vn + grp * DIM + c);
    o[0] += w.x; o[1] += w.y; o[2] += w.z; o[3] += w.w;
    uint2 pk;
    pk.x = pk2(o[0], o[1]);
    pk.y = pk2(o[2], o[3]);
    *(uint2*)(hin + base) = pk;
}

// ---------------------------------------------------------------- gather aggregation (bf16 in/out)
// z[n] = h_in[n] + sum_{e: dst=n} relu(h_in[src_e] + ea[e]@We + be)
__global__ __launch_bounds__(256) void aggr_kernel(
    const int* __restrict__ rowptr, const int2* __restrict__ sE,
    const float* __restrict__ ea,
    const float* __restrict__ Wel, const float* __restrict__ bel,
    const u16* __restrict__ hin, u16* __restrict__ z)
{
    int node = blockIdx.x * 4 + (threadIdx.x >> 6);
    if (node >= N_NODES) return;
    int lane = threadIdx.x & 63;
    int c = lane * 2;

    float2 rW[EFEAT];
    #pragma unroll
    for (int k = 0; k < EFEAT; ++k)
        rW[k] = *(const float2*)(Wel + k * DIM + c);
    const float2 rB = *(const float2*)(bel + c);

    float2 acc = up2(*(const u32*)(hin + (size_t)node * DIM + c));
    int beg = rowptr[node], end = rowptr[node + 1];

    int i = beg;
    for (; i + 3 < end; i += 4) {
        int2 s0 = sE[i], s1 = sE[i + 1], s2 = sE[i + 2], s3 = sE[i + 3];
        u32 h0 = *(const u32*)(hin + (size_t)s0.x * DIM + c);
        u32 h1 = *(const u32*)(hin + (size_t)s1.x * DIM + c);
        u32 h2 = *(const u32*)(hin + (size_t)s2.x * DIM + c);
        u32 h3 = *(const u32*)(hin + (size_t)s3.x * DIM + c);
        const float4 a0l = *(const float4*)(ea + (size_t)s0.y * EFEAT);
        const float4 a0h = *(const float4*)(ea + (size_t)s0.y * EFEAT + 4);
        const float4 a1l = *(const float4*)(ea + (size_t)s1.y * EFEAT);
        const float4 a1h = *(const float4*)(ea + (size_t)s1.y * EFEAT + 4);
        const float4 a2l = *(const float4*)(ea + (size_t)s2.y * EFEAT);
        const float4 a2h = *(const float4*)(ea + (size_t)s2.y * EFEAT + 4);
        const float4 a3l = *(const float4*)(ea + (size_t)s3.y * EFEAT);
        const float4 a3h = *(const float4*)(ea + (size_t)s3.y * EFEAT + 4);
        float ak0[8] = {a0l.x, a0l.y, a0l.z, a0l.w, a0h.x, a0h.y, a0h.z, a0h.w};
        float ak1[8] = {a1l.x, a1l.y, a1l.z, a1l.w, a1h.x, a1h.y, a1h.z, a1h.w};
        float ak2[8] = {a2l.x, a2l.y, a2l.z, a2l.w, a2h.x, a2h.y, a2h.z, a2h.w};
        float ak3[8] = {a3l.x, a3l.y, a3l.z, a3l.w, a3h.x, a3h.y, a3h.z, a3h.w};
        float e0x = rB.x, e0y = rB.y, e1x = rB.x, e1y = rB.y;
        float e2x = rB.x, e2y = rB.y, e3x = rB.x, e3y = rB.y;
        #pragma unroll
        for (int k = 0; k < EFEAT; ++k) {
            e0x = fmaf(ak0[k], rW[k].x, e0x); e0y = fmaf(ak0[k], rW[k].y, e0y);
            e1x = fmaf(ak1[k], rW[k].x, e1x); e1y = fmaf(ak1[k], rW[k].y, e1y);
            e2x = fmaf(ak2[k], rW[k].x, e2x); e2y = fmaf(ak2[k], rW[k].y, e2y);
            e3x = fmaf(ak3[k], rW[k].x, e3x); e3y = fmaf(ak3[k], rW[k].y, e3y);
        }
        float2 v0 = up2(h0), v1 = up2(h1), v2 = up2(h2), v3 = up2(h3);
        acc.x += fmaxf(v0.x + e0x, 0.f) + fmaxf(v1.x + e1x, 0.f)
               + fmaxf(v2.x + e2x, 0.f) + fmaxf(v3.x + e3x, 0.f);
        acc.y += fmaxf(v0.y + e0y, 0.f) + fmaxf(v1.y + e1y, 0.f)
               + fmaxf(v2.y + e2y, 0.f) + fmaxf(v3.y + e3y, 0.f);
    }
    for (; i < end; ++i) {
        int2 s0 = sE[i];
        u32 h0 = *(const u32*)(hin + (size_t)s0.x * DIM + c);
        const float4 a0l = *(const float4*)(ea + (size_t)s0.y * EFEAT);
        const float4 a0h = *(const float4*)(ea + (size_t)s0.y * EFEAT + 4);
        float ak0[8] = {a0l.x, a0l.y, a0l.z, a0l.w, a0h.x, a0h.y, a0h.z, a0h.w};
        float e0x = rB.x, e0y = rB.y;
        #pragma unroll
        for (int k = 0; k < EFEAT; ++k) {
            e0x = fmaf(ak0[k], rW[k].x, e0x);
            e0y = fmaf(ak0[k], rW[k].y, e0y);
        }
        float2 v0 = up2(h0);
        acc.x += fmaxf(v0.x + e0x, 0.f);
        acc.y += fmaxf(v0.y + e0y, 0.f);
    }
    *(u32*)(z + (size_t)node * DIM + c) = pk2(acc.x, acc.y);
}

// ---------------------------------------------------------------- bf16 MFMA GEMM, 128x64 tile, BK=128
// C = act(A) @ B^T_layout + bias ; epilogue accumulates per-column sum & sumsq
// MODE 0: A used as-is. MODE 1: A -> relu(alpha[k]*A + beta[k]) during staging.
// CBF16: store C as bf16, else fp32.
template <int MODE, bool CBF16>
__global__ __launch_bounds__(256) void gemm_bf16_kernel(
    const u16* __restrict__ Aa,          // [M][K] bf16
    const float* __restrict__ sSum, const float* __restrict__ sSS,
    const float* __restrict__ gA, const float* __restrict__ btA, float invCnt,
    const u16* __restrict__ Bt,          // [Nc][K] bf16 (pre-transposed)
    const float* __restrict__ bias,
    void* __restrict__ CoutV,
    float* __restrict__ outSum, float* __restrict__ outSS,
    int M, int K, int Nc)
{
    constexpr int BM = 128, BN = 64, BK = 128;
    constexpr int LDA = BK + 8;          // +8 bf16 (16B) pad: 2-way bank alias only
    __shared__ u16 As[BM * LDA];
    __shared__ u16 Bs[BN * LDA];
    __shared__ float csum[BN], css[BN];

    const int tid = threadIdx.x;
    const int wave = tid >> 6, lane = tid & 63;
    const int row0 = blockIdx.x * BM, col0 = blockIdx.y * BN;
    const int w_m = (wave & 1) * 64, w_n = (wave >> 1) * 32;
    const int quad = lane >> 4, l16 = lane & 15;

    if (tid < BN) { csum[tid] = 0.f; css[tid] = 0.f; }

    f32x4_t acc[4][2];
    #pragma unroll
    for (int mi = 0; mi < 4; ++mi)
        #pragma unroll
        for (int ni = 0; ni < 2; ++ni)
            acc[mi][ni] = (f32x4_t){0.f, 0.f, 0.f, 0.f};

    const int kc = (tid & 15) * 8;       // this thread's fixed k-offset within BK (ushorts)
    const int nkt = K / BK;

    for (int kt = 0; kt < nkt; ++kt) {
        float af[8], bf_[8];
        if (MODE == 1) {
            #pragma unroll
            for (int j = 0; j < 8; ++j) {
                int kg = kt * BK + kc + j;
                float m = sSum[kg] * invCnt;
                float var = sSS[kg] * invCnt - m * m;
                float r = rsqrtf(var + BN_EPS);
                float a = gA[kg] * r;
                af[j] = a;
                bf_[j] = btA[kg] - m * a;
            }
        }
        // stage A: 128 rows x 128 k, 8 iters x 256 threads x 16B
        #pragma unroll
        for (int it = 0; it < 8; ++it) {
            int chunk = it * 256 + tid;
            int row = chunk >> 4;
            int gr = row0 + row; if (gr >= M) gr = M - 1;
            uint4 q = *(const uint4*)(Aa + (size_t)gr * K + kt * BK + kc);
            if (MODE == 1) {
                float2 p0 = up2(q.x), p1 = up2(q.y), p2 = up2(q.z), p3 = up2(q.w);
                p0.x = fmaxf(fmaf(af[0], p0.x, bf_[0]), 0.f);
                p0.y = fmaxf(fmaf(af[1], p0.y, bf_[1]), 0.f);
                p1.x = fmaxf(fmaf(af[2], p1.x, bf_[2]), 0.f);
                p1.y = fmaxf(fmaf(af[3], p1.y, bf_[3]), 0.f);
                p2.x = fmaxf(fmaf(af[4], p2.x, bf_[4]), 0.f);
                p2.y = fmaxf(fmaf(af[5], p2.y, bf_[5]), 0.f);
                p3.x = fmaxf(fmaf(af[6], p3.x, bf_[6]), 0.f);
                p3.y = fmaxf(fmaf(af[7], p3.y, bf_[7]), 0.f);
                q.x = pk2(p0.x, p0.y); q.y = pk2(p1.x, p1.y);
                q.z = pk2(p2.x, p2.y); q.w = pk2(p3.x, p3.y);
            }
            *(uint4*)(As + row * LDA + kc) = q;
        }
        // stage B: 64 rows x 128 k, 4 iters
        #pragma unroll
        for (int it = 0; it < 4; ++it) {
            int chunk = it * 256 + tid;
            int n = chunk >> 4;
            uint4 q = *(const uint4*)(Bt + (size_t)(col0 + n) * K + kt * BK + kc);
            *(uint4*)(Bs + n * LDA + kc) = q;
        }
        __syncthreads();

        #pragma unroll
        for (int ks = 0; ks < 4; ++ks) {
            bf16x8_t a_frag[4], b_frag[2];
            #pragma unroll
            for (int mi = 0; mi < 4; ++mi)
                a_frag[mi] = *(const bf16x8_t*)(As + (w_m + mi * 16 + l16) * LDA + ks * 32 + quad * 8);
            #pragma unroll
            for (int ni = 0; ni < 2; ++ni)
                b_frag[ni] = *(const bf16x8_t*)(Bs + (w_n + ni * 16 + l16) * LDA + ks * 32 + quad * 8);
            #pragma unroll
            for (int mi = 0; mi < 4; ++mi)
                #pragma unroll
                for (int ni = 0; ni < 2; ++ni)
                    acc[mi][ni] = __builtin_amdgcn_mfma_f32_16x16x32_bf16(
                        a_frag[mi], b_frag[ni], acc[mi][ni], 0, 0, 0);
        }
        __syncthreads();
    }

    // epilogue: bias, store (C layout: col=lane&15, row=quad*4+reg), column stats
    u16* Cb = (u16*)CoutV;
    float* Cf = (float*)CoutV;
    #pragma unroll
    for (int ni = 0; ni < 2; ++ni) {
        int col = col0 + w_n + ni * 16 + l16;
        float bv = bias[col];
        float s = 0.f, qsum = 0.f;
        #pragma unroll
        for (int mi = 0; mi < 4; ++mi) {
            int rbase = row0 + w_m + mi * 16 + quad * 4;
            #pragma unroll
            for (int reg = 0; reg < 4; ++reg) {
                int gr = rbase + reg;
                if (gr < M) {
                    float o = acc[mi][ni][reg] + bv;
                    s += o;
                    qsum += o * o;
                    if (CBF16) Cb[(size_t)gr * Nc + col] = f2bf(o);
                    else       Cf[(size_t)gr * Nc + col] = o;
                }
            }
        }
        s += __shfl_xor(s, 16);  s += __shfl_xor(s, 32);
        qsum += __shfl_xor(qsum, 16);  qsum += __shfl_xor(qsum, 32);
        if (quad == 0) {
            atomicAdd(&csum[w_n + ni * 16 + l16], s);
            atomicAdd(&css[w_n + ni * 16 + l16], qsum);
        }
    }
    __syncthreads();
    if (tid < BN) {
        atomic_add_f(outSum + col0 + tid, csum[tid]);
        atomic_add_f(outSS + col0 + tid, css[tid]);
    }
}

// ---------------------------------------------------------------- fp32 GEMM (VN path, tiny M)
template <int MODE>
__global__ __launch_bounds__(256) void gemm_kernel(
    const float* __restrict__ Aa,
    const float* __restrict__ sSum, const float* __restrict__ sSS,
    const float* __restrict__ gA, const float* __restrict__ btA, float invCnt,
    const float* __restrict__ B, const float* __restrict__ bias,
    float* __restrict__ Cout, float* __restrict__ outSum, float* __restrict__ outSS,
    int M, int K, int Nc)
{
    __shared__ float As[16][68];
    __shared__ float Bs[16][64];
    __shared__ float alphaS[256], betaS[256];
    __shared__ float csum[64], css[64];

    const int tid = threadIdx.x;
    const int tx = tid & 15, ty = tid >> 4;
    const int row0 = blockIdx.x * 64, col0 = blockIdx.y * 64;

    if (tid < 64) { csum[tid] = 0.f; css[tid] = 0.f; }
    if (MODE == 1) {
        for (int k = tid; k < K; k += 256) {
            float m = sSum[k] * invCnt;
            float var = sSS[k] * invCnt - m * m;
            float r = rsqrtf(var + BN_EPS);
            float a = gA[k] * r;
            alphaS[k] = a;
            betaS[k] = btA[k] - m * a;
        }
    }
    __syncthreads();

    float acc[4][4];
    #pragma unroll
    for (int i = 0; i < 4; ++i)
        #pragma unroll
        for (int j = 0; j < 4; ++j) acc[i][j] = 0.f;

    const int lr = tid >> 2;
    const int lk = (tid & 3) * 4;
    const int bk = tid >> 4;
    const int bc = tx * 4;

    for (int kt = 0; kt < K; kt += 16) {
        int gr = row0 + lr;
        float4 va = make_float4(0.f, 0.f, 0.f, 0.f);
        if (gr < M) {
            va = *(const float4*)(Aa + (size_t)gr * K + kt + lk);
            if (MODE == 1) {
                int k0 = kt + lk;
                va.x = fmaxf(fmaf(alphaS[k0 + 0], va.x, betaS[k0 + 0]), 0.f);
                va.y = fmaxf(fmaf(alphaS[k0 + 1], va.y, betaS[k0 + 1]), 0.f);
                va.z = fmaxf(fmaf(alphaS[k0 + 2], va.z, betaS[k0 + 2]), 0.f);
                va.w = fmaxf(fmaf(alphaS[k0 + 3], va.w, betaS[k0 + 3]), 0.f);
            }
        }
        As[lk + 0][lr] = va.x;
        As[lk + 1][lr] = va.y;
        As[lk + 2][lr] = va.z;
        As[lk + 3][lr] = va.w;
        const float4 vb4 = *(const float4*)(B + (size_t)(kt + bk) * Nc + col0 + bc);
        *(float4*)&Bs[bk][bc] = vb4;
        __syncthreads();
        #pragma unroll
        for (int kk = 0; kk < 16; ++kk) {
            const float4 a4 = *(const float4*)&As[kk][ty * 4];
            const float4 b4 = *(const float4*)&Bs[kk][tx * 4];
            float av[4] = {a4.x, a4.y, a4.z, a4.w};
            float bv4[4] = {b4.x, b4.y, b4.z, b4.w};
            #pragma unroll
            for (int i = 0; i < 4; ++i)
                #pragma unroll
                for (int j = 0; j < 4; ++j)
                    acc[i][j] = fmaf(av[i], bv4[j], acc[i][j]);
        }
        __syncthreads();
    }

    const float4 bvv = *(const float4*)(bias + col0 + tx * 4);
    float bias4[4] = {bvv.x, bvv.y, bvv.z, bvv.w};
    float ps[4] = {0.f, 0.f, 0.f, 0.f};
    float pq[4] = {0.f, 0.f, 0.f, 0.f};
    #pragma unroll
    for (int i = 0; i < 4; ++i) {
        int gr = row0 + ty * 4 + i;
        if (gr < M) {
            float o[4];
            #pragma unroll
            for (int j = 0; j < 4; ++j) {
                o[j] = acc[i][j] + bias4[j];
                ps[j] += o[j];
                pq[j] += o[j] * o[j];
            }
            *(float4*)(Cout + (size_t)gr * Nc + col0 + tx * 4) = make_float4(o[0], o[1], o[2], o[3]);
        }
    }
    #pragma unroll
    for (int j = 0; j < 4; ++j) {
        atomicAdd(&csum[tx * 4 + j], ps[j]);
        atomicAdd(&css[tx * 4 + j], pq[j]);
    }
    __syncthreads();
    if (tid < 64) {
        atomic_add_f(outSum + col0 + tid, csum[tid]);
        atomic_add_f(outSS + col0 + tid, css[tid]);
    }
}

// ---------------------------------------------------------------- pooled[g] = vn[g] + segment_sum(h_in, batch)[g]
__global__ __launch_bounds__(128) void pooled_seg_kernel(
    const u16* __restrict__ hin, const int* __restrict__ batch,
    const float* __restrict__ vn, float* __restrict__ pooled)
{
    int g = blockIdx.x;
    int c = threadIdx.x;
    int lo = 0, hi = N_NODES;
    while (lo < hi) { int mid = (lo + hi) >> 1; if (batch[mid] < g) lo = mid + 1; else hi = mid; }
    int start = lo;
    hi = N_NODES;
    while (lo < hi) { int mid = (lo + hi) >> 1; if (batch[mid] < g + 1) lo = mid + 1; else hi = mid; }
    int end = lo;
    float acc = vn[g * DIM + c];
    for (int n = start; n < end; ++n) acc += bf2f(hin[(size_t)n * DIM + c]);
    pooled[g * DIM + c] = acc;
}

// ---------------------------------------------------------------- vn = relu(bn(vnpre))
__global__ void vn_apply_kernel(
    const float* __restrict__ vnpre, const float* __restrict__ vsum, const float* __restrict__ vss,
    const float* __restrict__ g, const float* __restrict__ b, float invG, float* __restrict__ vn)
{
    int idx = blockIdx.x * 256 + threadIdx.x;
    int total4 = N_GRAPH * DIM / 4;
    if (idx >= total4) return;
    int base = idx * 4;
    int c = base & (DIM - 1);
    float4 v = *(const float4*)(vnpre + base);
    float o[4] = {v.x, v.y, v.z, v.w};
    #pragma unroll
    for (int j = 0; j < 4; ++j) {
        int cj = c + j;
        float m = vsum[cj] * invG;
        float var = vss[cj] * invG - m * m;
        float r = rsqrtf(var + BN_EPS);
        float a = g[cj] * r;
        o[j] = fmaxf(fmaf(a, o[j], b[cj] - m * a), 0.f);
    }
    *(float4*)(vn + base) = make_float4(o[0], o[1], o[2], o[3]);
}

// ---------------------------------------------------------------- final in-place BN on d_out (no relu)
__global__ __launch_bounds__(256) void final_bn_kernel(
    float* __restrict__ outp, const float* __restrict__ sum2, const float* __restrict__ ss2,
    const float* __restrict__ g, const float* __restrict__ b, float invN, int total4)
{
    int idx = blockIdx.x * 256 + threadIdx.x;
    if (idx >= total4) return;
    int base = idx * 4;
    int c = base & (DIM - 1);
    float4 v = *(const float4*)(outp + base);
    float o[4] = {v.x, v.y, v.z, v.w};
    #pragma unroll
    for (int j = 0; j < 4; ++j) {
        int cj = c + j;
        float m = sum2[cj] * invN;
        float var = ss2[cj] * invN - m * m;
        float r = rsqrtf(var + BN_EPS);
        float a = g[cj] * r;
        o[j] = fmaf(a, o[j], b[cj] - m * a);
    }
    *(float4*)(outp + base) = make_float4(o[0], o[1], o[2], o[3]);
}

// ---------------------------------------------------------------- launch
extern "C" void kernel_launch(void* const* d_in, const int* in_sizes, int n_in,
                              void* d_out, int out_size, void* d_ws, size_t ws_size,
                              hipStream_t stream) {
    const float* x         = (const float*)d_in[0];
    const float* edge_attr = (const float*)d_in[1];
    const float* vn_emb    = (const float*)d_in[2];
    const float* We        = (const float*)d_in[3];
    const float* be        = (const float*)d_in[4];
    const float* W1        = (const float*)d_in[5];
    const float* b1        = (const float*)d_in[6];
    const float* g1v       = (const float*)d_in[7];
    const float* bt1       = (const float*)d_in[8];
    const float* W2        = (const float*)d_in[9];
    const float* b2        = (const float*)d_in[10];
    const float* gb        = (const float*)d_in[11];
    const float* bb        = (const float*)d_in[12];
    const float* Wv1       = (const float*)d_in[13];
    const float* bv1       = (const float*)d_in[14];
    const float* gv1       = (const float*)d_in[15];
    const float* btv1      = (const float*)d_in[16];
    const float* Wv2       = (const float*)d_in[17];
    const float* bv2       = (const float*)d_in[18];
    const float* gv2       = (const float*)d_in[19];
    const float* btv2      = (const float*)d_in[20];
    const int* edge_index  = (const int*)d_in[21];
    const int* batch       = (const int*)d_in[22];
    float* outp = (float*)d_out;

    char* wsb = (char*)d_ws;
    u16* h_in   = (u16*)wsb;                          wsb += (size_t)N_NODES * DIM * 2;   // 12.8 MB
    u16* z_bf   = (u16*)wsb;                          wsb += (size_t)N_NODES * DIM * 2;   // 12.8 MB
    u16* c1_bf  = (u16*)wsb;                          wsb += (size_t)N_NODES * HID * 2;   // 25.6 MB
    u16* W1t    = (u16*)wsb;                          wsb += (size_t)3 * 32768 * 2;
    u16* W2t    = (u16*)wsb;                          wsb += (size_t)3 * 32768 * 2;
    float* vn     = (float*)wsb;                      wsb += (size_t)N_GRAPH * DIM * 4;
    float* pooled = (float*)wsb;                      wsb += (size_t)N_GRAPH * DIM * 4;
    float* tpre   = (float*)wsb;                      wsb += (size_t)N_GRAPH * HID * 4;
    float* vnpre  = (float*)wsb;                      wsb += (size_t)N_GRAPH * DIM * 4;
    float* stats  = (float*)wsb;                      wsb += 2048 * 4;
    float* sum1 = stats,        *ss1 = stats + 256;
    float* sum2 = stats + 512,  *ss2 = stats + 640;
    float* vsum1 = stats + 768, *vss1 = stats + 1024;
    float* vsum2 = stats + 1280, *vss2 = stats + 1408;
    int* rowptr = (int*)wsb;                          wsb += (size_t)(N_NODES + 1) * 4;
    int* cursor = (int*)wsb;                          wsb += (size_t)(N_NODES + 3) * 4;
    int2* sE    = (int2*)wsb;

    const float invN = 1.0f / (float)N_NODES;
    const float invG = 1.0f / (float)N_GRAPH;
    const int total4 = N_NODES * DIM / 4;

    // ---- one-time prep: CSR, vn init, weight convert ----
    hipMemsetAsync(cursor, 0, N_NODES * sizeof(int), stream);
    hist_kernel<<<(N_EDGES + 255) / 256, 256, 0, stream>>>(edge_index, cursor);
    scan_kernel<<<1, 1024, 0, stream>>>(cursor, rowptr);
    hipMemsetAsync(cursor, 0, N_NODES * sizeof(int), stream);
    scatter_kernel<<<(N_EDGES + 255) / 256, 256, 0, stream>>>(edge_index, rowptr, cursor, sE);
    init_vn_kernel<<<(N_GRAPH * DIM + 255) / 256, 256, 0, stream>>>(vn_emb, vn);
    wconv_kernel<<<768, 256, 0, stream>>>(W1, W2, W1t, W2t);

    for (int l = 0; l < N_LAYER; ++l) {
        if (l == 0)
            hin_kernel<false><<<(total4 + 255) / 256, 256, 0, stream>>>(
                x, nullptr, nullptr, nullptr, nullptr, 0.f, batch, vn, h_in, total4);
        else
            hin_kernel<true><<<(total4 + 255) / 256, 256, 0, stream>>>(
                outp, sum2, ss2, gb + (size_t)(l - 1) * DIM, bb + (size_t)(l - 1) * DIM,
                invN, batch, vn, h_in, total4);

        hipMemsetAsync(stats, 0, 2048 * sizeof(float), stream);

        aggr_kernel<<<(N_NODES + 3) / 4, 256, 0, stream>>>(
            rowptr, sE, edge_attr, We + (size_t)l * EFEAT * DIM, be + (size_t)l * DIM,
            h_in, z_bf);

        // c1 = z @ W1 + b1 (bf16 out, stats -> sum1/ss1)
        dim3 g1d((N_NODES + 127) / 128, HID / 64);
        gemm_bf16_kernel<0, true><<<g1d, 256, 0, stream>>>(
            z_bf, nullptr, nullptr, nullptr, nullptr, 0.f,
            W1t + (size_t)l * 32768, b1 + (size_t)l * HID,
            (void*)c1_bf, sum1, ss1, N_NODES, DIM, HID);

        // h = relu(bn(c1)) @ W2 + b2 (fp32 out, stats -> sum2/ss2)
        dim3 g2d((N_NODES + 127) / 128, DIM / 64);
        gemm_bf16_kernel<1, false><<<g2d, 256, 0, stream>>>(
            c1_bf, sum1, ss1, g1v + (size_t)l * HID, bt1 + (size_t)l * HID, invN,
            W2t + (size_t)l * 32768, b2 + (size_t)l * DIM,
            (void*)outp, sum2, ss2, N_NODES, HID, DIM);

        if (l < N_LAYER - 1) {
            pooled_seg_kernel<<<N_GRAPH, 128, 0, stream>>>(h_in, batch, vn, pooled);

            dim3 g3d(N_GRAPH / 64, HID / 64);
            gemm_kernel<0><<<g3d, 256, 0, stream>>>(
                pooled, nullptr, nullptr, nullptr, nullptr, 0.f,
                Wv1 + (size_t)l * DIM * HID, bv1 + (size_t)l * HID,
                tpre, vsum1, vss1, N_GRAPH, DIM, HID);

            dim3 g4d(N_GRAPH / 64, DIM / 64);
            gemm_kernel<1><<<g4d, 256, 0, stream>>>(
                tpre, vsum1, vss1, gv1 + (size_t)l * HID, btv1 + (size_t)l * HID, invG,
                Wv2 + (size_t)l * HID * DIM, bv2 + (size_t)l * DIM,
                vnpre, vsum2, vss2, N_GRAPH, HID, DIM);

            vn_apply_kernel<<<(N_GRAPH * DIM / 4 + 255) / 256, 256, 0, stream>>>(
                vnpre, vsum2, vss2, gv2 + (size_t)l * DIM, btv2 + (size_t)l * DIM, invG, vn);
        }
    }

    final_bn_kernel<<<(total4 + 255) / 256, 256, 0, stream>>>(
        outp, sum2, ss2, gb + (size_t)2 * DIM, bb + (size_t)2 * DIM, invN, total4);
}

// Round 4
// 975.496 us; speedup vs baseline: 5.2472x; 1.0119x over previous
//
#include <hip/hip_runtime.h>
#include <hip/hip_bf16.h>

#define N_NODES 50000
#define N_EDGES 800000
#define DIM 128
#define HID 256
#define N_GRAPH 512
#define N_LAYER 3
#define EFEAT 8
#define BN_EPS 1e-5f

typedef unsigned short u16;
typedef unsigned int u32;

using bf16x8_t = short __attribute__((ext_vector_type(8)));
using f32x4_t  = float __attribute__((ext_vector_type(4)));

// ---------------------------------------------------------------- utilities

__device__ __forceinline__ void atomic_add_f(float* p, float v) {
    unsafeAtomicAdd(p, v);
}
__device__ __forceinline__ u16 f2bf(float x) {
    union { float f; u32 u; } v; v.f = x;
    u32 r = v.u + 0x7FFF + ((v.u >> 16) & 1);
    return (u16)(r >> 16);
}
__device__ __forceinline__ float bf2f(u16 u) {
    union { u32 i; float f; } v; v.i = (u32)u << 16; return v.f;
}
__device__ __forceinline__ float2 up2(u32 p) {
    return make_float2(bf2f((u16)(p & 0xFFFF)), bf2f((u16)(p >> 16)));
}
__device__ __forceinline__ u32 pk2(float a, float b) {
    return (u32)f2bf(a) | ((u32)f2bf(b) << 16);
}

// ---------------------------------------------------------------- weight transpose+convert to bf16
__global__ __launch_bounds__(256) void wconv_kernel(
    const float* __restrict__ W1, const float* __restrict__ W2,
    u16* __restrict__ W1t, u16* __restrict__ W2t)
{
    int idx = blockIdx.x * 256 + threadIdx.x;
    if (idx >= 6 * 32768) return;
    int m = idx >> 15;
    int off = idx & 32767;
    int l = m >> 1;
    if ((m & 1) == 0) {
        int r = off >> 8, c = off & 255;
        W1t[(size_t)l * 32768 + c * 128 + r] = f2bf(W1[(size_t)l * 32768 + r * 256 + c]);
    } else {
        int r = off >> 7, c = off & 127;
        W2t[(size_t)l * 32768 + c * 256 + r] = f2bf(W2[(size_t)l * 32768 + r * 128 + c]);
    }
}

// ---------------------------------------------------------------- edge_attr -> bf16 (once)
__global__ __launch_bounds__(256) void eaconv_kernel(const float* __restrict__ ea, u16* __restrict__ eab) {
    int e = blockIdx.x * 256 + threadIdx.x;
    if (e >= N_EDGES) return;
    const float4 lo = *(const float4*)(ea + (size_t)e * EFEAT);
    const float4 hi = *(const float4*)(ea + (size_t)e * EFEAT + 4);
    uint4 q;
    q.x = pk2(lo.x, lo.y); q.y = pk2(lo.z, lo.w);
    q.z = pk2(hi.x, hi.y); q.w = pk2(hi.z, hi.w);
    *(uint4*)(eab + (size_t)e * EFEAT) = q;
}

// ---------------------------------------------------------------- CSR build
__global__ __launch_bounds__(256) void hist_kernel(const int* __restrict__ ei, int* __restrict__ deg) {
    int e = blockIdx.x * 256 + threadIdx.x;
    if (e < N_EDGES) atomicAdd(&deg[ei[N_EDGES + e]], 1);
}

__global__ __launch_bounds__(1024) void scan_kernel(const int* __restrict__ deg, int* __restrict__ rowptr) {
    __shared__ int wsum[16];
    __shared__ int carry;
    int tid = threadIdx.x;
    if (tid == 0) { carry = 0; rowptr[0] = 0; }
    __syncthreads();
    for (int base = 0; base < N_NODES; base += 1024) {
        int i = base + tid;
        int v = (i < N_NODES) ? deg[i] : 0;
        int lane = tid & 63, w = tid >> 6;
        int s = v;
        #pragma unroll
        for (int d = 1; d < 64; d <<= 1) { int t = __shfl_up(s, d); if (lane >= d) s += t; }
        if (lane == 63) wsum[w] = s;
        __syncthreads();
        if (tid < 64) {
            int t = (tid < 16) ? wsum[tid] : 0;
            #pragma unroll
            for (int d = 1; d < 16; d <<= 1) { int u = __shfl_up(t, d); if (tid >= d) t += u; }
            if (tid < 16) wsum[tid] = t;
        }
        __syncthreads();
        int excl = (w > 0) ? wsum[w - 1] : 0;
        int incl = s + excl + carry;
        if (i < N_NODES) rowptr[i + 1] = incl;
        __syncthreads();
        if (tid == 0) carry += wsum[15];
        __syncthreads();
    }
}

__global__ __launch_bounds__(256) void scatter_kernel(
    const int* __restrict__ ei, const int* __restrict__ rowptr,
    int* __restrict__ cursor, int2* __restrict__ sE)
{
    int e = blockIdx.x * 256 + threadIdx.x;
    if (e >= N_EDGES) return;
    int dst = ei[N_EDGES + e];
    int p = atomicAdd(&cursor[dst], 1);
    sE[rowptr[dst] + p] = make_int2(ei[e], e);
}

// ---------------------------------------------------------------- h_in = act(src) + vn[batch]  (bf16 out)
// USEBN: apply BN(sum2/ss2,g,b)+relu to src.  VNM 0: vn = vn_emb row.  VNM 1: vn = relu(bnV(vnpre)).
template <bool USEBN, int VNM>
__global__ __launch_bounds__(256) void hin_kernel(
    const float* __restrict__ src,
    const float* __restrict__ sum2, const float* __restrict__ ss2,
    const float* __restrict__ g, const float* __restrict__ b, float invN,
    const int* __restrict__ batch,
    const float* __restrict__ vn_emb,
    const float* __restrict__ vnpre, const float* __restrict__ vsum, const float* __restrict__ vss,
    const float* __restrict__ gv, const float* __restrict__ btv, float invG,
    u16* __restrict__ hin, int total4)
{
    int idx = blockIdx.x * 256 + threadIdx.x;
    if (idx >= total4) return;
    int base = idx * 4;
    int n = base >> 7;
    int c = base & (DIM - 1);
    float4 v = *(const float4*)(src + base);
    float o[4] = {v.x, v.y, v.z, v.w};
    if (USEBN) {
        #pragma unroll
        for (int j = 0; j < 4; ++j) {
            int cj = c + j;
            float m = sum2[cj] * invN;
            float var = ss2[cj] * invN - m * m;
            float r = rsqrtf(var + BN_EPS);
            float a = g[cj] * r;
            o[j] = fmaxf(fmaf(a, o[j], b[cj] - m * a), 0.f);
        }
    }
    int grp = batch[n];
    if (VNM == 0) {
        const float4 w = *(const float4*)(vn_emb + c);
        o[0] += w.x; o[1] += w.y; o[2] += w.z; o[3] += w.w;
    } else {
        const float4 vp = *(const float4*)(vnpre + (size_t)grp * DIM + c);
        float vv[4] = {vp.x, vp.y, vp.z, vp.w};
        #pragma unroll
        for (int j = 0; j < 4; ++j) {
            int cj = c + j;
            float m = vsum[cj] * invG;
            float var = vss[cj] * invG - m * m;
            float r = rsqrtf(var + BN_EPS);
            float a = gv[cj] * r;
            o[j] += fmaxf(fmaf(a, vv[j], btv[cj] - m * a), 0.f);
        }
    }
    uint2 pk;
    pk.x = pk2(o[0], o[1]);
    pk.y = pk2(o[2], o[3]);
    *(uint2*)(hin + base) = pk;
}

// ---------------------------------------------------------------- gather aggregation (bf16, unroll-8)
__device__ __forceinline__ void edge_term(
    u32 h, uint4 eq, const float2* rW, float2 rB, float2& acc)
{
    float a[8];
    float2 p;
    p = up2(eq.x); a[0] = p.x; a[1] = p.y;
    p = up2(eq.y); a[2] = p.x; a[3] = p.y;
    p = up2(eq.z); a[4] = p.x; a[5] = p.y;
    p = up2(eq.w); a[6] = p.x; a[7] = p.y;
    float ex = rB.x, ey = rB.y;
    #pragma unroll
    for (int k = 0; k < EFEAT; ++k) {
        ex = fmaf(a[k], rW[k].x, ex);
        ey = fmaf(a[k], rW[k].y, ey);
    }
    float2 hv = up2(h);
    acc.x += fmaxf(hv.x + ex, 0.f);
    acc.y += fmaxf(hv.y + ey, 0.f);
}

__global__ __launch_bounds__(256) void aggr_kernel(
    const int* __restrict__ rowptr, const int2* __restrict__ sE,
    const u16* __restrict__ eab,
    const float* __restrict__ Wel, const float* __restrict__ bel,
    const u16* __restrict__ hin, u16* __restrict__ z)
{
    int node = blockIdx.x * 4 + (threadIdx.x >> 6);
    if (node >= N_NODES) return;
    int lane = threadIdx.x & 63;
    int c = lane * 2;

    float2 rW[EFEAT];
    #pragma unroll
    for (int k = 0; k < EFEAT; ++k)
        rW[k] = *(const float2*)(Wel + k * DIM + c);
    const float2 rB = *(const float2*)(bel + c);

    float2 acc = up2(*(const u32*)(hin + (size_t)node * DIM + c));
    int beg = rowptr[node], end = rowptr[node + 1];

    int i = beg;
    if ((i & 1) && i < end) {   // peel to even index for int4-paired sE loads
        int2 s0 = sE[i];
        u32 h0 = *(const u32*)(hin + (size_t)s0.x * DIM + c);
        uint4 e0 = *(const uint4*)(eab + (size_t)s0.y * EFEAT);
        edge_term(h0, e0, rW, rB, acc);
        ++i;
    }
    for (; i + 7 < end; i += 8) {
        int4 sp0 = *(const int4*)(sE + i);
        int4 sp1 = *(const int4*)(sE + i + 2);
        int4 sp2 = *(const int4*)(sE + i + 4);
        int4 sp3 = *(const int4*)(sE + i + 6);
        u32 h0 = *(const u32*)(hin + (size_t)sp0.x * DIM + c);
        u32 h1 = *(const u32*)(hin + (size_t)sp0.z * DIM + c);
        u32 h2 = *(const u32*)(hin + (size_t)sp1.x * DIM + c);
        u32 h3 = *(const u32*)(hin + (size_t)sp1.z * DIM + c);
        u32 h4 = *(const u32*)(hin + (size_t)sp2.x * DIM + c);
        u32 h5 = *(const u32*)(hin + (size_t)sp2.z * DIM + c);
        u32 h6 = *(const u32*)(hin + (size_t)sp3.x * DIM + c);
        u32 h7 = *(const u32*)(hin + (size_t)sp3.z * DIM + c);
        uint4 e0 = *(const uint4*)(eab + (size_t)sp0.y * EFEAT);
        uint4 e1 = *(const uint4*)(eab + (size_t)sp0.w * EFEAT);
        uint4 e2 = *(const uint4*)(eab + (size_t)sp1.y * EFEAT);
        uint4 e3 = *(const uint4*)(eab + (size_t)sp1.w * EFEAT);
        uint4 e4 = *(const uint4*)(eab + (size_t)sp2.y * EFEAT);
        uint4 e5 = *(const uint4*)(eab + (size_t)sp2.w * EFEAT);
        uint4 e6 = *(const uint4*)(eab + (size_t)sp3.y * EFEAT);
        uint4 e7 = *(const uint4*)(eab + (size_t)sp3.w * EFEAT);
        edge_term(h0, e0, rW, rB, acc);
        edge_term(h1, e1, rW, rB, acc);
        edge_term(h2, e2, rW, rB, acc);
        edge_term(h3, e3, rW, rB, acc);
        edge_term(h4, e4, rW, rB, acc);
        edge_term(h5, e5, rW, rB, acc);
        edge_term(h6, e6, rW, rB, acc);
        edge_term(h7, e7, rW, rB, acc);
    }
    for (; i < end; ++i) {
        int2 s0 = sE[i];
        u32 h0 = *(const u32*)(hin + (size_t)s0.x * DIM + c);
        uint4 e0 = *(const uint4*)(eab + (size_t)s0.y * EFEAT);
        edge_term(h0, e0, rW, rB, acc);
    }
    *(u32*)(z + (size_t)node * DIM + c) = pk2(acc.x, acc.y);
}

// ---------------------------------------------------------------- bf16 MFMA GEMM, 128x128 tile (two B-halves), BK=128
// MODE 0: A as-is. MODE 1: A -> relu(alpha[k]*A+beta[k]) during staging. CBF16: C stored bf16 else fp32.
template <int MODE, bool CBF16>
__global__ __launch_bounds__(256) void gemm_bf16_kernel(
    const u16* __restrict__ Aa,
    const float* __restrict__ sSum, const float* __restrict__ sSS,
    const float* __restrict__ gA, const float* __restrict__ btA, float invCnt,
    const u16* __restrict__ Bt,          // [Nc][K] bf16
    const float* __restrict__ bias,
    void* __restrict__ CoutV,
    float* __restrict__ outSum, float* __restrict__ outSS,
    int M, int K, int Nc)
{
    constexpr int BM = 128, BN = 128, BK = 128;
    constexpr int LDA = BK + 8;
    __shared__ u16 As[BM * LDA];         // 34.8 KB
    __shared__ u16 Bs[64 * LDA];         // 17.4 KB
    __shared__ float csum[BN], css[BN];

    const int tid = threadIdx.x;
    const int wave = tid >> 6, lane = tid & 63;
    const int row0 = blockIdx.x * BM, col0 = blockIdx.y * BN;
    const int w_m = (wave & 1) * 64, w_n = (wave >> 1) * 32;
    const int quad = lane >> 4, l16 = lane & 15;

    if (tid < BN) { csum[tid] = 0.f; css[tid] = 0.f; }

    f32x4_t acc[4][4];                   // [mi][half*2+ni]
    #pragma unroll
    for (int mi = 0; mi < 4; ++mi)
        #pragma unroll
        for (int ni = 0; ni < 4; ++ni)
            acc[mi][ni] = (f32x4_t){0.f, 0.f, 0.f, 0.f};

    const int kc = (tid & 15) * 8;
    const int nkt = K / BK;

    for (int kt = 0; kt < nkt; ++kt) {
        float af[8], bf_[8];
        if (MODE == 1) {
            #pragma unroll
            for (int j = 0; j < 8; ++j) {
                int kg = kt * BK + kc + j;
                float m = sSum[kg] * invCnt;
                float var = sSS[kg] * invCnt - m * m;
                float r = rsqrtf(var + BN_EPS);
                float a = gA[kg] * r;
                af[j] = a;
                bf_[j] = btA[kg] - m * a;
            }
        }
        // stage A: 128 rows x 128 k
        #pragma unroll
        for (int it = 0; it < 8; ++it) {
            int chunk = it * 256 + tid;
            int row = chunk >> 4;
            int gr = row0 + row; if (gr >= M) gr = M - 1;
            uint4 q = *(const uint4*)(Aa + (size_t)gr * K + kt * BK + kc);
            if (MODE == 1) {
                float2 p0 = up2(q.x), p1 = up2(q.y), p2 = up2(q.z), p3 = up2(q.w);
                p0.x = fmaxf(fmaf(af[0], p0.x, bf_[0]), 0.f);
                p0.y = fmaxf(fmaf(af[1], p0.y, bf_[1]), 0.f);
                p1.x = fmaxf(fmaf(af[2], p1.x, bf_[2]), 0.f);
                p1.y = fmaxf(fmaf(af[3], p1.y, bf_[3]), 0.f);
                p2.x = fmaxf(fmaf(af[4], p2.x, bf_[4]), 0.f);
                p2.y = fmaxf(fmaf(af[5], p2.y, bf_[5]), 0.f);
                p3.x = fmaxf(fmaf(af[6], p3.x, bf_[6]), 0.f);
                p3.y = fmaxf(fmaf(af[7], p3.y, bf_[7]), 0.f);
                q.x = pk2(p0.x, p0.y); q.y = pk2(p1.x, p1.y);
                q.z = pk2(p2.x, p2.y); q.w = pk2(p3.x, p3.y);
            }
            *(uint4*)(As + row * LDA + kc) = q;
        }
        #pragma unroll
        for (int half = 0; half < 2; ++half) {
            // stage B half: 64 cols x 128 k
            #pragma unroll
            for (int it = 0; it < 4; ++it) {
                int chunk = it * 256 + tid;
                int n = chunk >> 4;
                uint4 q = *(const uint4*)(Bt + (size_t)(col0 + half * 64 + n) * K + kt * BK + kc);
                *(uint4*)(Bs + n * LDA + kc) = q;
            }
            __syncthreads();
            #pragma unroll
            for (int ks = 0; ks < 4; ++ks) {
                bf16x8_t a_frag[4], b_frag[2];
                #pragma unroll
                for (int mi = 0; mi < 4; ++mi)
                    a_frag[mi] = *(const bf16x8_t*)(As + (w_m + mi * 16 + l16) * LDA + ks * 32 + quad * 8);
                #pragma unroll
                for (int ni = 0; ni < 2; ++ni)
                    b_frag[ni] = *(const bf16x8_t*)(Bs + (w_n + ni * 16 + l16) * LDA + ks * 32 + quad * 8);
                #pragma unroll
                for (int mi = 0; mi < 4; ++mi)
                    #pragma unroll
                    for (int ni = 0; ni < 2; ++ni)
                        acc[mi][half * 2 + ni] = __builtin_amdgcn_mfma_f32_16x16x32_bf16(
                            a_frag[mi], b_frag[ni], acc[mi][half * 2 + ni], 0, 0, 0);
            }
            __syncthreads();
        }
    }

    // epilogue
    u16* Cb = (u16*)CoutV;
    float* Cf = (float*)CoutV;
    #pragma unroll
    for (int half = 0; half < 2; ++half)
    #pragma unroll
    for (int ni = 0; ni < 2; ++ni) {
        int ccol = half * 64 + w_n + ni * 16 + l16;
        int col = col0 + ccol;
        float bv = bias[col];
        float s = 0.f, qs = 0.f;
        #pragma unroll
        for (int mi = 0; mi < 4; ++mi) {
            int rbase = row0 + w_m + mi * 16 + quad * 4;
            #pragma unroll
            for (int reg = 0; reg < 4; ++reg) {
                int gr = rbase + reg;
                if (gr < M) {
                    float o = acc[mi][half * 2 + ni][reg] + bv;
                    s += o;
                    qs += o * o;
                    if (CBF16) Cb[(size_t)gr * Nc + col] = f2bf(o);
                    else       Cf[(size_t)gr * Nc + col] = o;
                }
            }
        }
        s += __shfl_xor(s, 16);  s += __shfl_xor(s, 32);
        qs += __shfl_xor(qs, 16);  qs += __shfl_xor(qs, 32);
        if (quad == 0) {
            atomicAdd(&csum[ccol], s);
            atomicAdd(&css[ccol], qs);
        }
    }
    __syncthreads();
    if (tid < BN) {
        atomic_add_f(outSum + col0 + tid, csum[tid]);
        atomic_add_f(outSS + col0 + tid, css[tid]);
    }
}

// ---------------------------------------------------------------- fp32 GEMM (VN path, tiny M)
template <int MODE>
__global__ __launch_bounds__(256) void gemm_kernel(
    const float* __restrict__ Aa,
    const float* __restrict__ sSum, const float* __restrict__ sSS,
    const float* __restrict__ gA, const float* __restrict__ btA, float invCnt,
    const float* __restrict__ B, const float* __restrict__ bias,
    float* __restrict__ Cout, float* __restrict__ outSum, float* __restrict__ outSS,
    int M, int K, int Nc)
{
    __shared__ float As[16][68];
    __shared__ float Bs[16][64];
    __shared__ float alphaS[256], betaS[256];
    __shared__ float csum[64], css[64];

    const int tid = threadIdx.x;
    const int tx = tid & 15, ty = tid >> 4;
    const int row0 = blockIdx.x * 64, col0 = blockIdx.y * 64;

    if (tid < 64) { csum[tid] = 0.f; css[tid] = 0.f; }
    if (MODE == 1) {
        for (int k = tid; k < K; k += 256) {
            float m = sSum[k] * invCnt;
            float var = sSS[k] * invCnt - m * m;
            float r = rsqrtf(var + BN_EPS);
            float a = gA[k] * r;
            alphaS[k] = a;
            betaS[k] = btA[k] - m * a;
        }
    }
    __syncthreads();

    float acc[4][4];
    #pragma unroll
    for (int i = 0; i < 4; ++i)
        #pragma unroll
        for (int j = 0; j < 4; ++j) acc[i][j] = 0.f;

    const int lr = tid >> 2;
    const int lk = (tid & 3) * 4;
    const int bk = tid >> 4;
    const int bc = tx * 4;

    for (int kt = 0; kt < K; kt += 16) {
        int gr = row0 + lr;
        float4 va = make_float4(0.f, 0.f, 0.f, 0.f);
        if (gr < M) {
            va = *(const float4*)(Aa + (size_t)gr * K + kt + lk);
            if (MODE == 1) {
                int k0 = kt + lk;
                va.x = fmaxf(fmaf(alphaS[k0 + 0], va.x, betaS[k0 + 0]), 0.f);
                va.y = fmaxf(fmaf(alphaS[k0 + 1], va.y, betaS[k0 + 1]), 0.f);
                va.z = fmaxf(fmaf(alphaS[k0 + 2], va.z, betaS[k0 + 2]), 0.f);
                va.w = fmaxf(fmaf(alphaS[k0 + 3], va.w, betaS[k0 + 3]), 0.f);
            }
        }
        As[lk + 0][lr] = va.x;
        As[lk + 1][lr] = va.y;
        As[lk + 2][lr] = va.z;
        As[lk + 3][lr] = va.w;
        const float4 vb4 = *(const float4*)(B + (size_t)(kt + bk) * Nc + col0 + bc);
        *(float4*)&Bs[bk][bc] = vb4;
        __syncthreads();
        #pragma unroll
        for (int kk = 0; kk < 16; ++kk) {
            const float4 a4 = *(const float4*)&As[kk][ty * 4];
            const float4 b4 = *(const float4*)&Bs[kk][tx * 4];
            float av[4] = {a4.x, a4.y, a4.z, a4.w};
            float bv4[4] = {b4.x, b4.y, b4.z, b4.w};
            #pragma unroll
            for (int i = 0; i < 4; ++i)
                #pragma unroll
                for (int j = 0; j < 4; ++j)
                    acc[i][j] = fmaf(av[i], bv4[j], acc[i][j]);
        }
        __syncthreads();
    }

    const float4 bvv = *(const float4*)(bias + col0 + tx * 4);
    float bias4[4] = {bvv.x, bvv.y, bvv.z, bvv.w};
    float ps[4] = {0.f, 0.f, 0.f, 0.f};
    float pq[4] = {0.f, 0.f, 0.f, 0.f};
    #pragma unroll
    for (int i = 0; i < 4; ++i) {
        int gr = row0 + ty * 4 + i;
        if (gr < M) {
            float o[4];
            #pragma unroll
            for (int j = 0; j < 4; ++j) {
                o[j] = acc[i][j] + bias4[j];
                ps[j] += o[j];
                pq[j] += o[j] * o[j];
            }
            *(float4*)(Cout + (size_t)gr * Nc + col0 + tx * 4) = make_float4(o[0], o[1], o[2], o[3]);
        }
    }
    #pragma unroll
    for (int j = 0; j < 4; ++j) {
        atomicAdd(&csum[tx * 4 + j], ps[j]);
        atomicAdd(&css[tx * 4 + j], pq[j]);
    }
    __syncthreads();
    if (tid < 64) {
        atomic_add_f(outSum + col0 + tid, csum[tid]);
        atomic_add_f(outSS + col0 + tid, css[tid]);
    }
}

// ---------------------------------------------------------------- pooled[g] = vn[g] + segment_sum(h_in, batch)[g]
template <int VNM>
__global__ __launch_bounds__(128) void pooled_seg_kernel(
    const u16* __restrict__ hin, const int* __restrict__ batch,
    const float* __restrict__ vn_emb,
    const float* __restrict__ vnpre, const float* __restrict__ vsum, const float* __restrict__ vss,
    const float* __restrict__ gv, const float* __restrict__ btv, float invG,
    float* __restrict__ pooled)
{
    int g = blockIdx.x;
    int c = threadIdx.x;
    int lo = 0, hi = N_NODES;
    while (lo < hi) { int mid = (lo + hi) >> 1; if (batch[mid] < g) lo = mid + 1; else hi = mid; }
    int start = lo;
    hi = N_NODES;
    while (lo < hi) { int mid = (lo + hi) >> 1; if (batch[mid] < g + 1) lo = mid + 1; else hi = mid; }
    int end = lo;
    float acc;
    if (VNM == 0) {
        acc = vn_emb[c];
    } else {
        float m = vsum[c] * invG;
        float var = vss[c] * invG - m * m;
        float r = rsqrtf(var + BN_EPS);
        float a = gv[c] * r;
        acc = fmaxf(fmaf(a, vnpre[(size_t)g * DIM + c], btv[c] - m * a), 0.f);
    }
    for (int n = start; n < end; ++n) acc += bf2f(hin[(size_t)n * DIM + c]);
    pooled[(size_t)g * DIM + c] = acc;
}

// ---------------------------------------------------------------- final in-place BN on d_out (no relu)
__global__ __launch_bounds__(256) void final_bn_kernel(
    float* __restrict__ outp, const float* __restrict__ sum2, const float* __restrict__ ss2,
    const float* __restrict__ g, const float* __restrict__ b, float invN, int total4)
{
    int idx = blockIdx.x * 256 + threadIdx.x;
    if (idx >= total4) return;
    int base = idx * 4;
    int c = base & (DIM - 1);
    float4 v = *(const float4*)(outp + base);
    float o[4] = {v.x, v.y, v.z, v.w};
    #pragma unroll
    for (int j = 0; j < 4; ++j) {
        int cj = c + j;
        float m = sum2[cj] * invN;
        float var = ss2[cj] * invN - m * m;
        float r = rsqrtf(var + BN_EPS);
        float a = g[cj] * r;
        o[j] = fmaf(a, o[j], b[cj] - m * a);
    }
    *(float4*)(outp + base) = make_float4(o[0], o[1], o[2], o[3]);
}

// ---------------------------------------------------------------- launch
extern "C" void kernel_launch(void* const* d_in, const int* in_sizes, int n_in,
                              void* d_out, int out_size, void* d_ws, size_t ws_size,
                              hipStream_t stream) {
    const float* x         = (const float*)d_in[0];
    const float* edge_attr = (const float*)d_in[1];
    const float* vn_emb    = (const float*)d_in[2];
    const float* We        = (const float*)d_in[3];
    const float* be        = (const float*)d_in[4];
    const float* W1        = (const float*)d_in[5];
    const float* b1        = (const float*)d_in[6];
    const float* g1v       = (const float*)d_in[7];
    const float* bt1       = (const float*)d_in[8];
    const float* W2        = (const float*)d_in[9];
    const float* b2        = (const float*)d_in[10];
    const float* gb        = (const float*)d_in[11];
    const float* bb        = (const float*)d_in[12];
    const float* Wv1       = (const float*)d_in[13];
    const float* bv1       = (const float*)d_in[14];
    const float* gv1       = (const float*)d_in[15];
    const float* btv1      = (const float*)d_in[16];
    const float* Wv2       = (const float*)d_in[17];
    const float* bv2       = (const float*)d_in[18];
    const float* gv2       = (const float*)d_in[19];
    const float* btv2      = (const float*)d_in[20];
    const int* edge_index  = (const int*)d_in[21];
    const int* batch       = (const int*)d_in[22];
    float* outp = (float*)d_out;

    auto au = [](size_t x) { return (x + 255) & ~(size_t)255; };
    char* p = (char*)d_ws;
    u16* h_in   = (u16*)p;  p += au((size_t)N_NODES * DIM * 2);
    u16* z_bf   = (u16*)p;  p += au((size_t)N_NODES * DIM * 2);
    u16* c1_bf  = (u16*)p;  p += au((size_t)N_NODES * HID * 2);
    u16* eab    = (u16*)p;  p += au((size_t)N_EDGES * EFEAT * 2);
    u16* W1t    = (u16*)p;  p += au((size_t)3 * 32768 * 2);
    u16* W2t    = (u16*)p;  p += au((size_t)3 * 32768 * 2);
    float* pooled = (float*)p;  p += au((size_t)N_GRAPH * DIM * 4);
    float* tpre   = (float*)p;  p += au((size_t)N_GRAPH * HID * 4);
    float* vnpre  = (float*)p;  p += au((size_t)N_GRAPH * DIM * 4);
    float* stats  = (float*)p;  p += au(2048 * 4);
    float* sum1 = stats,        *ss1 = stats + 256;
    float* sum2 = stats + 512,  *ss2 = stats + 640;
    float* vsum1 = stats + 768, *vss1 = stats + 1024;
    float* vsum2 = stats + 1280, *vss2 = stats + 1408;
    int* rowptr = (int*)p;  p += au((size_t)(N_NODES + 1) * 4);
    int* cursor = (int*)p;  p += au((size_t)N_NODES * 4);
    int2* sE    = (int2*)p;

    const float invN = 1.0f / (float)N_NODES;
    const float invG = 1.0f / (float)N_GRAPH;
    const int total4 = N_NODES * DIM / 4;

    // ---- one-time prep: CSR, weight/edge convert ----
    hipMemsetAsync(cursor, 0, N_NODES * sizeof(int), stream);
    hist_kernel<<<(N_EDGES + 255) / 256, 256, 0, stream>>>(edge_index, cursor);
    scan_kernel<<<1, 1024, 0, stream>>>(cursor, rowptr);
    hipMemsetAsync(cursor, 0, N_NODES * sizeof(int), stream);
    scatter_kernel<<<(N_EDGES + 255) / 256, 256, 0, stream>>>(edge_index, rowptr, cursor, sE);
    wconv_kernel<<<768, 256, 0, stream>>>(W1, W2, W1t, W2t);
    eaconv_kernel<<<(N_EDGES + 255) / 256, 256, 0, stream>>>(edge_attr, eab);

    for (int l = 0; l < N_LAYER; ++l) {
        if (l == 0)
            hin_kernel<false, 0><<<(total4 + 255) / 256, 256, 0, stream>>>(
                x, nullptr, nullptr, nullptr, nullptr, 0.f, batch,
                vn_emb, nullptr, nullptr, nullptr, nullptr, nullptr, 0.f,
                h_in, total4);
        else
            hin_kernel<true, 1><<<(total4 + 255) / 256, 256, 0, stream>>>(
                outp, sum2, ss2, gb + (size_t)(l - 1) * DIM, bb + (size_t)(l - 1) * DIM, invN, batch,
                nullptr, vnpre, vsum2, vss2,
                gv2 + (size_t)(l - 1) * DIM, btv2 + (size_t)(l - 1) * DIM, invG,
                h_in, total4);

        // pooled only needed for l < L-1; uses h_in and the SAME vn used by hin
        if (l == 0)
            pooled_seg_kernel<0><<<N_GRAPH, 128, 0, stream>>>(
                h_in, batch, vn_emb, nullptr, nullptr, nullptr, nullptr, nullptr, 0.f, pooled);
        else if (l < N_LAYER - 1)
            pooled_seg_kernel<1><<<N_GRAPH, 128, 0, stream>>>(
                h_in, batch, nullptr, vnpre, vsum2, vss2,
                gv2 + (size_t)(l - 1) * DIM, btv2 + (size_t)(l - 1) * DIM, invG, pooled);

        hipMemsetAsync(stats, 0, 2048 * sizeof(float), stream);

        aggr_kernel<<<(N_NODES + 3) / 4, 256, 0, stream>>>(
            rowptr, sE, eab, We + (size_t)l * EFEAT * DIM, be + (size_t)l * DIM,
            h_in, z_bf);

        // c1 = z @ W1 + b1 (bf16 out, stats -> sum1/ss1)
        dim3 g1d((N_NODES + 127) / 128, HID / 128);
        gemm_bf16_kernel<0, true><<<g1d, 256, 0, stream>>>(
            z_bf, nullptr, nullptr, nullptr, nullptr, 0.f,
            W1t + (size_t)l * 32768, b1 + (size_t)l * HID,
            (void*)c1_bf, sum1, ss1, N_NODES, DIM, HID);

        // h = relu(bn(c1)) @ W2 + b2 (fp32 out, stats -> sum2/ss2)
        dim3 g2d((N_NODES + 127) / 128, DIM / 128);
        gemm_bf16_kernel<1, false><<<g2d, 256, 0, stream>>>(
            c1_bf, sum1, ss1, g1v + (size_t)l * HID, bt1 + (size_t)l * HID, invN,
            W2t + (size_t)l * 32768, b2 + (size_t)l * DIM,
            (void*)outp, sum2, ss2, N_NODES, HID, DIM);

        if (l < N_LAYER - 1) {
            dim3 g3d(N_GRAPH / 64, HID / 64);
            gemm_kernel<0><<<g3d, 256, 0, stream>>>(
                pooled, nullptr, nullptr, nullptr, nullptr, 0.f,
                Wv1 + (size_t)l * DIM * HID, bv1 + (size_t)l * HID,
                tpre, vsum1, vss1, N_GRAPH, DIM, HID);

            dim3 g4d(N_GRAPH / 64, DIM / 64);
            gemm_kernel<1><<<g4d, 256, 0, stream>>>(
                tpre, vsum1, vss1, gv1 + (size_t)l * HID, btv1 + (size_t)l * HID, invG,
                Wv2 + (size_t)l * HID * DIM, bv2 + (size_t)l * DIM,
                vnpre, vsum2, vss2, N_GRAPH, HID, DIM);
        }
    }

    final_bn_kernel<<<(total4 + 255) / 256, 256, 0, stream>>>(
        outp, sum2, ss2, gb + (size_t)2 * DIM, bb + (size_t)2 * DIM, invN, total4);
}